// Round 1
// baseline (637.174 us; speedup 1.0000x reference)
//
#include <hip/hip_runtime.h>

#define NDIM 256
#define INNER 512
#define NH 8
#define ND 64
#define NS 32
#define NB 8

// ---------------------------------------------------------------------------
// Kernel 1: fx = x@Wfx+bfx ; xm = x@Wx+bx ; logits=(xm.Wslice+bsl)/temp ;
//           w = softmax_s(logits).  One block = 64 nodes x 1 head (64 cols).
// ---------------------------------------------------------------------------
__global__ __launch_bounds__(256) void k_fxw(
    const float* __restrict__ x,
    const float* __restrict__ Wfx, const float* __restrict__ bfx,
    const float* __restrict__ Wx,  const float* __restrict__ bx,
    const float* __restrict__ Wsl, const float* __restrict__ bsl,
    const float* __restrict__ gtemp,
    float* __restrict__ fx_out, float* __restrict__ w_out, int N)
{
  __shared__ float As[16][68];     // transposed A tile, padded (16B-aligned rows)
  __shared__ float Bf[16][64];
  __shared__ float Bm[16][64];
  __shared__ float xm_s[64][65];
  __shared__ float Ws_s[64][32];

  const int h = blockIdx.x;
  const int row0 = blockIdx.y * 64;
  const int tid = threadIdx.x;
  const int colbase = h * 64;

  for (int i = tid; i < 64 * 32; i += 256) Ws_s[i >> 5][i & 31] = Wsl[i];

  const int tr = tid >> 4, tc = tid & 15;
  const int r0 = tr * 4, c0 = tc * 4;
  float accf[4][4] = {{0}}, accm[4][4] = {{0}};

  for (int k0 = 0; k0 < NDIM; k0 += 16) {
    {
      int r = tid >> 2;             // 0..63
      int k4 = (tid & 3) * 4;       // 0,4,8,12
      int rr = row0 + r;
      float4 v = make_float4(0.f, 0.f, 0.f, 0.f);
      if (rr < N) v = *(const float4*)&x[(size_t)rr * NDIM + k0 + k4];
      As[k4 + 0][r] = v.x; As[k4 + 1][r] = v.y;
      As[k4 + 2][r] = v.z; As[k4 + 3][r] = v.w;
    }
    {
      int k = tid >> 4;             // 0..15
      int c4 = (tid & 15) * 4;
      float4 vf = *(const float4*)&Wfx[(size_t)(k0 + k) * INNER + colbase + c4];
      float4 vm = *(const float4*)&Wx [(size_t)(k0 + k) * INNER + colbase + c4];
      *(float4*)&Bf[k][c4] = vf;
      *(float4*)&Bm[k][c4] = vm;
    }
    __syncthreads();
    #pragma unroll
    for (int kk = 0; kk < 16; kk++) {
      float4 a4 = *(const float4*)&As[kk][r0];
      float4 f4 = *(const float4*)&Bf[kk][c0];
      float4 m4 = *(const float4*)&Bm[kk][c0];
      float a[4] = {a4.x, a4.y, a4.z, a4.w};
      float f[4] = {f4.x, f4.y, f4.z, f4.w};
      float m[4] = {m4.x, m4.y, m4.z, m4.w};
      #pragma unroll
      for (int i = 0; i < 4; i++)
        #pragma unroll
        for (int j = 0; j < 4; j++) {
          accf[i][j] += a[i] * f[j];
          accm[i][j] += a[i] * m[j];
        }
    }
    __syncthreads();
  }

  // epilogue: bias, write fx (float4), stash xm in LDS
  #pragma unroll
  for (int i = 0; i < 4; i++) {
    int rr = row0 + r0 + i;
    float4 fv, mv;
    float* fp = &fv.x; float* mp = &mv.x;
    #pragma unroll
    for (int j = 0; j < 4; j++) {
      int cc = colbase + c0 + j;
      fp[j] = accf[i][j] + bfx[cc];
      mp[j] = accm[i][j] + bx[cc];
      xm_s[r0 + i][c0 + j] = mp[j];
    }
    if (rr < N) *(float4*)&fx_out[(size_t)rr * INNER + colbase + c0] = fv;
  }
  __syncthreads();

  // logits + tempered softmax -> w
  const float inv_t = 1.0f / gtemp[h];
  const int s = tid & 31, rg = tid >> 5;
  for (int ii = 0; ii < 8; ii++) {
    int r = rg + 8 * ii;
    float acc = bsl[s];
    #pragma unroll 8
    for (int dd = 0; dd < 64; dd++) acc += xm_s[r][dd] * Ws_s[dd][s];
    float lg = acc * inv_t;
    float mx = lg;
    for (int off = 16; off > 0; off >>= 1) mx = fmaxf(mx, __shfl_xor(mx, off, 32));
    float ev = __expf(lg - mx);
    float sum = ev;
    for (int off = 16; off > 0; off >>= 1) sum += __shfl_xor(sum, off, 32);
    int rr = row0 + r;
    if (rr < N) w_out[(size_t)rr * (NH * NS) + h * NS + s] = ev / sum;
  }
}

// ---------------------------------------------------------------------------
// Kernel 2: scatter-accumulate slice_token[b,h,s,d] += w[n,h,s]*fx[n,h,d]
//           and slice_norm[b,h,s] += w[n,h,s].  batch is sorted.
// Block = 512-node chunk x 1 head; per-thread 8 (s,d) register accumulators,
// flushed with atomics when b changes (block-uniform) and at the end.
// ---------------------------------------------------------------------------
__global__ __launch_bounds__(256) void k_scatter(
    const float* __restrict__ fx, const float* __restrict__ w,
    const int* __restrict__ batch,
    float* __restrict__ stok, float* __restrict__ snorm, int N)
{
  __shared__ float w_sh[64][32];
  __shared__ float fx_sh[64][64];
  __shared__ int b_sh[64];
  const int h = blockIdx.y;
  const int n0 = blockIdx.x * 512;
  const int tid = threadIdx.x;
  const int d = tid & 63, sg = tid >> 6;   // 4 s-groups of 8
  float acc[8] = {0, 0, 0, 0, 0, 0, 0, 0};
  float nacc = 0.f;
  int cur_b = batch[n0];
  const int nend = min(n0 + 512, N);

  for (int t0 = n0; t0 < nend; t0 += 64) {
    const int cnt = min(64, nend - t0);
    __syncthreads();
    for (int i = tid; i < cnt * 32; i += 256)
      w_sh[i >> 5][i & 31] = w[(size_t)(t0 + (i >> 5)) * (NH * NS) + h * NS + (i & 31)];
    for (int i = tid; i < cnt * 64; i += 256)
      fx_sh[i >> 6][i & 63] = fx[(size_t)(t0 + (i >> 6)) * INNER + h * ND + (i & 63)];
    if (tid < cnt) b_sh[tid] = batch[t0 + tid];
    __syncthreads();

    for (int r = 0; r < cnt; r++) {
      int bb = b_sh[r];
      if (bb != cur_b) {           // block-uniform branch (batch sorted)
        #pragma unroll
        for (int j = 0; j < 8; j++) {
          atomicAdd(&stok[(((size_t)cur_b * NH + h) * NS + sg * 8 + j) * ND + d], acc[j]);
          acc[j] = 0.f;
        }
        if (tid < 32) { atomicAdd(&snorm[((size_t)cur_b * NH + h) * NS + tid], nacc); nacc = 0.f; }
        cur_b = bb;
      }
      const float4* wp = (const float4*)&w_sh[r][sg * 8];
      float4 w0 = wp[0], w1 = wp[1];
      float f = fx_sh[r][d];
      acc[0] += w0.x * f; acc[1] += w0.y * f; acc[2] += w0.z * f; acc[3] += w0.w * f;
      acc[4] += w1.x * f; acc[5] += w1.y * f; acc[6] += w1.z * f; acc[7] += w1.w * f;
      if (tid < 32) nacc += w_sh[r][tid];
    }
  }
  #pragma unroll
  for (int j = 0; j < 8; j++)
    atomicAdd(&stok[(((size_t)cur_b * NH + h) * NS + sg * 8 + j) * ND + d], acc[j]);
  if (tid < 32) atomicAdd(&snorm[((size_t)cur_b * NH + h) * NS + tid], nacc);
}

// ---------------------------------------------------------------------------
// Kernel 3: per (b,h): normalize tokens, q/k/v, 32x32 attention, out_tok.
// ---------------------------------------------------------------------------
__global__ __launch_bounds__(256) void k_attn(
    const float* __restrict__ stok, const float* __restrict__ snorm,
    const float* __restrict__ Wq, const float* __restrict__ Wk,
    const float* __restrict__ Wv, float* __restrict__ out_tok)
{
  __shared__ float st[32][65];
  __shared__ float qs[32][65];
  __shared__ float ks[32][65];
  __shared__ float vs[32][65];
  __shared__ float at[32][33];
  const int bh = blockIdx.x;
  const int tid = threadIdx.x;

  for (int i = tid; i < 2048; i += 256) {
    int ss = i >> 6;
    float nrm = snorm[(size_t)bh * NS + ss] + 1e-5f;
    st[ss][i & 63] = stok[(size_t)bh * 2048 + i] / nrm;
  }
  __syncthreads();

  const int e = tid & 63, sgp = tid >> 6;
  for (int ii = 0; ii < 8; ii++) {
    int ss = sgp * 8 + ii;
    float aq = 0.f, ak = 0.f, av = 0.f;
    #pragma unroll 8
    for (int dd = 0; dd < 64; dd++) {
      float sv = st[ss][dd];
      aq += sv * Wq[dd * 64 + e];
      ak += sv * Wk[dd * 64 + e];
      av += sv * Wv[dd * 64 + e];
    }
    qs[ss][e] = aq; ks[ss][e] = ak; vs[ss][e] = av;
  }
  __syncthreads();

  const float scale = 0.125f;   // D^-0.5
  for (int i = tid; i < 1024; i += 256) {
    int si = i >> 5, tj = i & 31;
    float a = 0.f;
    #pragma unroll 8
    for (int ee = 0; ee < 64; ee++) a += qs[si][ee] * ks[tj][ee];
    at[si][tj] = a * scale;
  }
  __syncthreads();

  if (tid < 32) {
    float m = -1e30f;
    for (int j = 0; j < 32; j++) m = fmaxf(m, at[tid][j]);
    float sum = 0.f;
    for (int j = 0; j < 32; j++) { float ev = __expf(at[tid][j] - m); at[tid][j] = ev; sum += ev; }
    float inv = 1.f / sum;
    for (int j = 0; j < 32; j++) at[tid][j] *= inv;
  }
  __syncthreads();

  for (int ii = 0; ii < 8; ii++) {
    int ss = sgp * 8 + ii;
    float a = 0.f;
    #pragma unroll 8
    for (int tj = 0; tj < 32; tj++) a += at[ss][tj] * vs[tj][e];
    out_tok[(size_t)bh * 2048 + ss * 64 + e] = a;
  }
}

// ---------------------------------------------------------------------------
// Kernel 4: out_x[n, h*64+d] = sum_s w[n,h,s] * out_tok[batch[n],h,s,d]
// Block = 64 nodes x 1 head; segment-scan over sorted batch within tile.
// ---------------------------------------------------------------------------
__global__ __launch_bounds__(256) void k_gather(
    const float* __restrict__ w, const float* __restrict__ out_tok,
    const int* __restrict__ batch, float* __restrict__ out_x, int N)
{
  __shared__ float w_sh[64][32];
  __shared__ float tok[32][64];
  __shared__ int b_sh[64];
  const int h = blockIdx.y;
  const int n0 = blockIdx.x * 64;
  const int tid = threadIdx.x;
  const int cnt = min(64, N - n0);

  for (int i = tid; i < cnt * 32; i += 256)
    w_sh[i >> 5][i & 31] = w[(size_t)(n0 + (i >> 5)) * (NH * NS) + h * NS + (i & 31)];
  if (tid < cnt) b_sh[tid] = batch[n0 + tid];
  __syncthreads();

  const int d = tid & 63, ng = tid >> 6;
  int i = 0;
  while (i < cnt) {
    int b = b_sh[i];
    int j = i;
    while (j < cnt && b_sh[j] == b) j++;   // uniform scan
    __syncthreads();
    for (int t = tid; t < 2048; t += 256)
      tok[t >> 6][t & 63] = out_tok[((size_t)b * NH + h) * 2048 + t];
    __syncthreads();
    for (int r = i + ng; r < j; r += 4) {
      float a = 0.f;
      #pragma unroll 8
      for (int ss = 0; ss < 32; ss++) a += w_sh[r][ss] * tok[ss][d];
      out_x[(size_t)(n0 + r) * INNER + h * ND + d] = a;
    }
    i = j;
  }
}

// ---------------------------------------------------------------------------
// Kernel 5: out = out_x @ W_out + b_out   ([N,512]@[512,256])
// ---------------------------------------------------------------------------
__global__ __launch_bounds__(256) void k_gemm_out(
    const float* __restrict__ A, const float* __restrict__ W,
    const float* __restrict__ bias, float* __restrict__ out, int N)
{
  __shared__ float As[16][68];
  __shared__ float Bs[16][64];
  const int ct = blockIdx.x;          // 0..3
  const int row0 = blockIdx.y * 64;
  const int tid = threadIdx.x;
  const int colbase = ct * 64;
  const int tr = tid >> 4, tc = tid & 15;
  const int r0 = tr * 4, c0 = tc * 4;
  float acc[4][4] = {{0}};

  for (int k0 = 0; k0 < INNER; k0 += 16) {
    {
      int r = tid >> 2;
      int k4 = (tid & 3) * 4;
      int rr = row0 + r;
      float4 v = make_float4(0.f, 0.f, 0.f, 0.f);
      if (rr < N) v = *(const float4*)&A[(size_t)rr * INNER + k0 + k4];
      As[k4 + 0][r] = v.x; As[k4 + 1][r] = v.y;
      As[k4 + 2][r] = v.z; As[k4 + 3][r] = v.w;
    }
    {
      int k = tid >> 4;
      int c4 = (tid & 15) * 4;
      *(float4*)&Bs[k][c4] = *(const float4*)&W[(size_t)(k0 + k) * NDIM + colbase + c4];
    }
    __syncthreads();
    #pragma unroll
    for (int kk = 0; kk < 16; kk++) {
      float4 a4 = *(const float4*)&As[kk][r0];
      float4 b4 = *(const float4*)&Bs[kk][c0];
      float a[4] = {a4.x, a4.y, a4.z, a4.w};
      float b[4] = {b4.x, b4.y, b4.z, b4.w};
      #pragma unroll
      for (int i = 0; i < 4; i++)
        #pragma unroll
        for (int j = 0; j < 4; j++) acc[i][j] += a[i] * b[j];
    }
    __syncthreads();
  }
  #pragma unroll
  for (int i = 0; i < 4; i++) {
    int rr = row0 + r0 + i;
    if (rr >= N) continue;
    float4 o;
    o.x = acc[i][0] + bias[colbase + c0 + 0];
    o.y = acc[i][1] + bias[colbase + c0 + 1];
    o.z = acc[i][2] + bias[colbase + c0 + 2];
    o.w = acc[i][3] + bias[colbase + c0 + 3];
    *(float4*)&out[(size_t)rr * NDIM + colbase + c0] = o;
  }
}

// ---------------------------------------------------------------------------
extern "C" void kernel_launch(void* const* d_in, const int* in_sizes, int n_in,
                              void* d_out, int out_size, void* d_ws, size_t ws_size,
                              hipStream_t stream) {
  const float* x      = (const float*)d_in[0];
  const int*   batch  = (const int*)d_in[1];
  const float* Wfx    = (const float*)d_in[2];
  const float* bfx    = (const float*)d_in[3];
  const float* Wx     = (const float*)d_in[4];
  const float* bx     = (const float*)d_in[5];
  const float* Wsl    = (const float*)d_in[6];
  const float* bsl    = (const float*)d_in[7];
  const float* gtemp  = (const float*)d_in[8];
  const float* Wq     = (const float*)d_in[9];
  const float* Wk     = (const float*)d_in[10];
  const float* Wv     = (const float*)d_in[11];
  const float* Wout   = (const float*)d_in[12];
  const float* bout   = (const float*)d_in[13];
  float* out = (float*)d_out;

  const int N = in_sizes[0] / NDIM;   // 30000

  float* ws   = (float*)d_ws;
  float* fx   = ws;                               // [N,512]; reused as out_x
  float* w    = fx + (size_t)N * INNER;           // [N,256]
  float* stok = w + (size_t)N * (NH * NS);        // [B,H,S,D] = 131072
  float* snorm = stok + (size_t)NB * NH * NS * ND;    // 2048
  float* otok  = snorm + (size_t)NB * NH * NS;        // 131072

  // zero the scatter accumulators (ws is poisoned before every launch)
  hipMemsetAsync(stok, 0, (size_t)(NB * NH * NS * ND + NB * NH * NS) * sizeof(float), stream);

  dim3 g1(NH, (N + 63) / 64);
  k_fxw<<<g1, 256, 0, stream>>>(x, Wfx, bfx, Wx, bx, Wsl, bsl, gtemp, fx, w, N);

  dim3 g2((N + 511) / 512, NH);
  k_scatter<<<g2, 256, 0, stream>>>(fx, w, batch, stok, snorm, N);

  k_attn<<<NB * NH, 256, 0, stream>>>(stok, snorm, Wq, Wk, Wv, otok);

  dim3 g4((N + 63) / 64, NH);
  k_gather<<<g4, 256, 0, stream>>>(w, otok, batch, fx /*out_x*/, N);

  dim3 g5(NDIM / 64, (N + 63) / 64);
  k_gemm_out<<<g5, 256, 0, stream>>>(fx, Wout, bout, out, N);
}

// Round 2
// 424.348 us; speedup vs baseline: 1.5015x; 1.5015x over previous
//
#include <hip/hip_runtime.h>

#define NDIM 256
#define INNER 512
#define NH 8
#define ND 64
#define NS 32
#define NB 8

typedef __attribute__((ext_vector_type(8))) short short8;   // 8 bf16 = 4 VGPR
typedef __attribute__((ext_vector_type(4))) float f32x4;

static __device__ __forceinline__ short f2bf(float f) {
  unsigned u = __float_as_uint(f);
  unsigned r = (u + 0x7fffu + ((u >> 16) & 1u)) >> 16;
  return (short)r;
}
static __device__ __forceinline__ float bf2f(short s) {
  return __uint_as_float(((unsigned)(unsigned short)s) << 16);
}

// ---------------------------------------------------------------------------
// k_prep: build bf16 hi/lo packed, transposed B matrices in ws:
//  Bt1 [768][256]: rows 0..511 = Wfx^T; rows 512..767 = (Wx_h @ Wsl)^T (logits)
//  Bt2 [256][512]: Wout^T
//  bcomb[256] = bx_h @ Wsl + bsl
// ---------------------------------------------------------------------------
__global__ __launch_bounds__(256) void k_prep(
    const float* __restrict__ Wfx, const float* __restrict__ Wx,
    const float* __restrict__ bx, const float* __restrict__ Wsl,
    const float* __restrict__ bsl, const float* __restrict__ Wout,
    short* __restrict__ Bt1h, short* __restrict__ Bt1l,
    short* __restrict__ Bt2h, short* __restrict__ Bt2l,
    float* __restrict__ bcomb)
{
  int id = blockIdx.x * 256 + threadIdx.x;
  if (id < 131072) {                       // Wfx transpose: k-major read coalesced
    int k = id >> 9, n = id & 511;
    float v = Wfx[k * 512 + n];
    short hi = f2bf(v); short lo = f2bf(v - bf2f(hi));
    Bt1h[n * 256 + k] = hi; Bt1l[n * 256 + k] = lo;
  } else if (id < 196608) {                // Wcomb[k][c] = sum_d Wx[k][h*64+d]*Wsl[d][s]
    int e = id - 131072;
    int c = e & 255, k = e >> 8;
    int h = c >> 5, s = c & 31;
    float acc = 0.f;
    #pragma unroll 8
    for (int d = 0; d < 64; d++) acc += Wx[k * 512 + h * 64 + d] * Wsl[d * 32 + s];
    short hi = f2bf(acc); short lo = f2bf(acc - bf2f(hi));
    Bt1h[(512 + c) * 256 + k] = hi; Bt1l[(512 + c) * 256 + k] = lo;
  } else if (id < 327680) {                // Wout transpose
    int e = id - 196608;
    int k = e >> 8, n = e & 255;
    float v = Wout[k * 256 + n];
    short hi = f2bf(v); short lo = f2bf(v - bf2f(hi));
    Bt2h[n * 512 + k] = hi; Bt2l[n * 512 + k] = lo;
  } else if (id < 327936) {                // bcomb
    int c = id - 327680;
    int h = c >> 5, s = c & 31;
    float acc = bsl[s];
    #pragma unroll 8
    for (int d = 0; d < 64; d++) acc += bx[h * 64 + d] * Wsl[d * 32 + s];
    bcomb[c] = acc;
  }
}

// ---------------------------------------------------------------------------
// k_fxw: C[N,768] = x[N,256] @ Bt1^T via split-bf16 MFMA.
//  cols 0..511  -> fx_out (+ bfx)
//  cols 512..767 -> logits (+ bcomb), tempered softmax per 32-group -> w_out
// Grid: (6 col-tiles of 128, 235 row-tiles of 128). 256 thr = 4 waves (2x2).
// ---------------------------------------------------------------------------
__global__ __launch_bounds__(256) void k_fxw(
    const float* __restrict__ x,
    const short* __restrict__ Bt1h, const short* __restrict__ Bt1l,
    const float* __restrict__ bfx, const float* __restrict__ bcomb,
    const float* __restrict__ gtemp,
    float* __restrict__ fx_out, float* __restrict__ w_out, int N)
{
  __shared__ short Ah[128][40];   // [m][k], pitch 40 (80 B) to spread banks
  __shared__ short Al[128][40];
  __shared__ short Bh[128][40];   // [n][k]
  __shared__ short Bl[128][40];

  const int ct = blockIdx.x;           // col tile: cols [ct*128, ct*128+128)
  const int row0 = blockIdx.y * 128;
  const int tid = threadIdx.x;
  const int lane = tid & 63, l15 = lane & 15, quad = lane >> 4;
  const int wv = tid >> 6, wm = wv & 1, wn = wv >> 1;
  const int ctbase = ct * 128;

  f32x4 acc[4][4];
  #pragma unroll
  for (int i = 0; i < 4; i++)
    #pragma unroll
    for (int j = 0; j < 4; j++) acc[i][j] = (f32x4){0.f, 0.f, 0.f, 0.f};

  for (int kt = 0; kt < 8; kt++) {       // K = 256, BK = 32
    // stage A: 128 rows x 32 k, fp32 -> bf16 hi/lo
    #pragma unroll
    for (int t = 0; t < 4; t++) {
      int i = tid + t * 256;             // 1024 float4 chunks
      int row = i >> 3, kc = (i & 7) * 4;
      int gr = row0 + row;
      float4 v = make_float4(0.f, 0.f, 0.f, 0.f);
      if (gr < N) v = *(const float4*)&x[(size_t)gr * NDIM + kt * 32 + kc];
      short h0 = f2bf(v.x), h1 = f2bf(v.y), h2 = f2bf(v.z), h3 = f2bf(v.w);
      Ah[row][kc + 0] = h0; Ah[row][kc + 1] = h1;
      Ah[row][kc + 2] = h2; Ah[row][kc + 3] = h3;
      Al[row][kc + 0] = f2bf(v.x - bf2f(h0));
      Al[row][kc + 1] = f2bf(v.y - bf2f(h1));
      Al[row][kc + 2] = f2bf(v.z - bf2f(h2));
      Al[row][kc + 3] = f2bf(v.w - bf2f(h3));
    }
    // stage B: 128 rows x 32 k bf16, straight 16B copies
    #pragma unroll
    for (int t = 0; t < 2; t++) {
      int i = tid + t * 256;             // 512 16B chunks
      int row = i >> 2, kc = (i & 3) * 8;
      size_t src = (size_t)(ctbase + row) * 256 + kt * 32 + kc;
      *(int4*)&Bh[row][kc] = *(const int4*)&Bt1h[src];
      *(int4*)&Bl[row][kc] = *(const int4*)&Bt1l[src];
    }
    __syncthreads();

    short8 ah[4], al[4];
    #pragma unroll
    for (int mt = 0; mt < 4; mt++) {
      int m = wm * 64 + mt * 16 + l15;
      ah[mt] = *(const short8*)&Ah[m][quad * 8];
      al[mt] = *(const short8*)&Al[m][quad * 8];
    }
    #pragma unroll
    for (int nt = 0; nt < 4; nt++) {
      int n = wn * 64 + nt * 16 + l15;
      short8 bh = *(const short8*)&Bh[n][quad * 8];
      short8 bl = *(const short8*)&Bl[n][quad * 8];
      #pragma unroll
      for (int mt = 0; mt < 4; mt++) {
        acc[mt][nt] = __builtin_amdgcn_mfma_f32_16x16x32_bf16(ah[mt], bh, acc[mt][nt], 0, 0, 0);
        acc[mt][nt] = __builtin_amdgcn_mfma_f32_16x16x32_bf16(ah[mt], bl, acc[mt][nt], 0, 0, 0);
        acc[mt][nt] = __builtin_amdgcn_mfma_f32_16x16x32_bf16(al[mt], bh, acc[mt][nt], 0, 0, 0);
      }
    }
    __syncthreads();
  }

  if (ct < 4) {
    // fx epilogue: + bias, scalar stores (quarter-wave coalesced)
    #pragma unroll
    for (int nt = 0; nt < 4; nt++) {
      int c = ctbase + wn * 64 + nt * 16 + l15;
      float bias = bfx[c];
      #pragma unroll
      for (int mt = 0; mt < 4; mt++)
        #pragma unroll
        for (int r = 0; r < 4; r++) {
          int row = row0 + wm * 64 + mt * 16 + quad * 4 + r;
          if (row < N) fx_out[(size_t)row * INNER + c] = acc[mt][nt][r] + bias;
        }
    }
  } else {
    // logits -> tempered softmax over each 32-col group -> w
    int ct2 = ct - 4;
    #pragma unroll
    for (int g = 0; g < 2; g++) {
      int lcbase = ct2 * 128 + wn * 64 + g * 32;   // multiple of 32
      int h = lcbase >> 5;
      float inv_t = 1.0f / gtemp[h];
      int lc0 = lcbase + l15, lc1 = lcbase + 16 + l15;
      float b0 = bcomb[lc0], b1 = bcomb[lc1];
      #pragma unroll
      for (int mt = 0; mt < 4; mt++) {
        #pragma unroll
        for (int r = 0; r < 4; r++) {
          float s0 = (acc[mt][2 * g + 0][r] + b0) * inv_t;
          float s1 = (acc[mt][2 * g + 1][r] + b1) * inv_t;
          float m = fmaxf(s0, s1);
          #pragma unroll
          for (int off = 1; off < 16; off <<= 1) m = fmaxf(m, __shfl_xor(m, off, 16));
          float e0 = __expf(s0 - m), e1 = __expf(s1 - m);
          float sum = e0 + e1;
          #pragma unroll
          for (int off = 1; off < 16; off <<= 1) sum += __shfl_xor(sum, off, 16);
          float inv = 1.0f / sum;
          int row = row0 + wm * 64 + mt * 16 + quad * 4 + r;
          if (row < N) {
            w_out[(size_t)row * (NH * NS) + lc0] = e0 * inv;
            w_out[(size_t)row * (NH * NS) + lc1] = e1 * inv;
          }
        }
      }
    }
  }
}

// ---------------------------------------------------------------------------
// k_out: out[N,256] = out_x[N,512] @ Bt2^T + bout, split-bf16 MFMA.
// Grid: (2 col-tiles, 235 row-tiles).
// ---------------------------------------------------------------------------
__global__ __launch_bounds__(256) void k_out(
    const float* __restrict__ A,
    const short* __restrict__ B2h, const short* __restrict__ B2l,
    const float* __restrict__ bout, float* __restrict__ out, int N)
{
  __shared__ short Ah[128][40];
  __shared__ short Al[128][40];
  __shared__ short Bh[128][40];
  __shared__ short Bl[128][40];

  const int ct = blockIdx.x;
  const int row0 = blockIdx.y * 128;
  const int tid = threadIdx.x;
  const int lane = tid & 63, l15 = lane & 15, quad = lane >> 4;
  const int wv = tid >> 6, wm = wv & 1, wn = wv >> 1;
  const int ctbase = ct * 128;

  f32x4 acc[4][4];
  #pragma unroll
  for (int i = 0; i < 4; i++)
    #pragma unroll
    for (int j = 0; j < 4; j++) acc[i][j] = (f32x4){0.f, 0.f, 0.f, 0.f};

  for (int kt = 0; kt < 16; kt++) {      // K = 512, BK = 32
    #pragma unroll
    for (int t = 0; t < 4; t++) {
      int i = tid + t * 256;
      int row = i >> 3, kc = (i & 7) * 4;
      int gr = row0 + row;
      float4 v = make_float4(0.f, 0.f, 0.f, 0.f);
      if (gr < N) v = *(const float4*)&A[(size_t)gr * INNER + kt * 32 + kc];
      short h0 = f2bf(v.x), h1 = f2bf(v.y), h2 = f2bf(v.z), h3 = f2bf(v.w);
      Ah[row][kc + 0] = h0; Ah[row][kc + 1] = h1;
      Ah[row][kc + 2] = h2; Ah[row][kc + 3] = h3;
      Al[row][kc + 0] = f2bf(v.x - bf2f(h0));
      Al[row][kc + 1] = f2bf(v.y - bf2f(h1));
      Al[row][kc + 2] = f2bf(v.z - bf2f(h2));
      Al[row][kc + 3] = f2bf(v.w - bf2f(h3));
    }
    #pragma unroll
    for (int t = 0; t < 2; t++) {
      int i = tid + t * 256;
      int row = i >> 2, kc = (i & 3) * 8;
      size_t src = (size_t)(ctbase + row) * 512 + kt * 32 + kc;
      *(int4*)&Bh[row][kc] = *(const int4*)&B2h[src];
      *(int4*)&Bl[row][kc] = *(const int4*)&B2l[src];
    }
    __syncthreads();

    short8 ah[4], al[4];
    #pragma unroll
    for (int mt = 0; mt < 4; mt++) {
      int m = wm * 64 + mt * 16 + l15;
      ah[mt] = *(const short8*)&Ah[m][quad * 8];
      al[mt] = *(const short8*)&Al[m][quad * 8];
    }
    #pragma unroll
    for (int nt = 0; nt < 4; nt++) {
      int n = wn * 64 + nt * 16 + l15;
      short8 bh = *(const short8*)&Bh[n][quad * 8];
      short8 bl = *(const short8*)&Bl[n][quad * 8];
      #pragma unroll
      for (int mt = 0; mt < 4; mt++) {
        acc[mt][nt] = __builtin_amdgcn_mfma_f32_16x16x32_bf16(ah[mt], bh, acc[mt][nt], 0, 0, 0);
        acc[mt][nt] = __builtin_amdgcn_mfma_f32_16x16x32_bf16(ah[mt], bl, acc[mt][nt], 0, 0, 0);
        acc[mt][nt] = __builtin_amdgcn_mfma_f32_16x16x32_bf16(al[mt], bh, acc[mt][nt], 0, 0, 0);
      }
    }
    __syncthreads();
  }

  #pragma unroll
  for (int nt = 0; nt < 4; nt++) {
    int c = ctbase + wn * 64 + nt * 16 + l15;
    float bias = bout[c];
    #pragma unroll
    for (int mt = 0; mt < 4; mt++)
      #pragma unroll
      for (int r = 0; r < 4; r++) {
        int row = row0 + wm * 64 + mt * 16 + quad * 4 + r;
        if (row < N) out[(size_t)row * NDIM + c] = acc[mt][nt][r] + bias;
      }
  }
}

// ---------------------------------------------------------------------------
// Kernel 2: scatter-accumulate slice_token[b,h,s,d] += w[n,h,s]*fx[n,h,d]
// ---------------------------------------------------------------------------
__global__ __launch_bounds__(256) void k_scatter(
    const float* __restrict__ fx, const float* __restrict__ w,
    const int* __restrict__ batch,
    float* __restrict__ stok, float* __restrict__ snorm, int N)
{
  __shared__ float w_sh[64][32];
  __shared__ float fx_sh[64][64];
  __shared__ int b_sh[64];
  const int h = blockIdx.y;
  const int n0 = blockIdx.x * 512;
  const int tid = threadIdx.x;
  const int d = tid & 63, sg = tid >> 6;
  float acc[8] = {0, 0, 0, 0, 0, 0, 0, 0};
  float nacc = 0.f;
  int cur_b = batch[n0];
  const int nend = min(n0 + 512, N);

  for (int t0 = n0; t0 < nend; t0 += 64) {
    const int cnt = min(64, nend - t0);
    __syncthreads();
    for (int i = tid; i < cnt * 32; i += 256)
      w_sh[i >> 5][i & 31] = w[(size_t)(t0 + (i >> 5)) * (NH * NS) + h * NS + (i & 31)];
    for (int i = tid; i < cnt * 64; i += 256)
      fx_sh[i >> 6][i & 63] = fx[(size_t)(t0 + (i >> 6)) * INNER + h * ND + (i & 63)];
    if (tid < cnt) b_sh[tid] = batch[t0 + tid];
    __syncthreads();

    for (int r = 0; r < cnt; r++) {
      int bb = b_sh[r];
      if (bb != cur_b) {
        #pragma unroll
        for (int j = 0; j < 8; j++) {
          atomicAdd(&stok[(((size_t)cur_b * NH + h) * NS + sg * 8 + j) * ND + d], acc[j]);
          acc[j] = 0.f;
        }
        if (tid < 32) { atomicAdd(&snorm[((size_t)cur_b * NH + h) * NS + tid], nacc); nacc = 0.f; }
        cur_b = bb;
      }
      const float4* wp = (const float4*)&w_sh[r][sg * 8];
      float4 w0 = wp[0], w1 = wp[1];
      float f = fx_sh[r][d];
      acc[0] += w0.x * f; acc[1] += w0.y * f; acc[2] += w0.z * f; acc[3] += w0.w * f;
      acc[4] += w1.x * f; acc[5] += w1.y * f; acc[6] += w1.z * f; acc[7] += w1.w * f;
      if (tid < 32) nacc += w_sh[r][tid];
    }
  }
  #pragma unroll
  for (int j = 0; j < 8; j++)
    atomicAdd(&stok[(((size_t)cur_b * NH + h) * NS + sg * 8 + j) * ND + d], acc[j]);
  if (tid < 32) atomicAdd(&snorm[((size_t)cur_b * NH + h) * NS + tid], nacc);
}

// ---------------------------------------------------------------------------
// Kernel 3: per (b,h): normalize tokens, q/k/v, 32x32 attention, out_tok.
// ---------------------------------------------------------------------------
__global__ __launch_bounds__(256) void k_attn(
    const float* __restrict__ stok, const float* __restrict__ snorm,
    const float* __restrict__ Wq, const float* __restrict__ Wk,
    const float* __restrict__ Wv, float* __restrict__ out_tok)
{
  __shared__ float st[32][65];
  __shared__ float qs[32][65];
  __shared__ float ks[32][65];
  __shared__ float vs[32][65];
  __shared__ float at[32][33];
  const int bh = blockIdx.x;
  const int tid = threadIdx.x;

  for (int i = tid; i < 2048; i += 256) {
    int ss = i >> 6;
    float nrm = snorm[(size_t)bh * NS + ss] + 1e-5f;
    st[ss][i & 63] = stok[(size_t)bh * 2048 + i] / nrm;
  }
  __syncthreads();

  const int e = tid & 63, sgp = tid >> 6;
  for (int ii = 0; ii < 8; ii++) {
    int ss = sgp * 8 + ii;
    float aq = 0.f, ak = 0.f, av = 0.f;
    #pragma unroll 8
    for (int dd = 0; dd < 64; dd++) {
      float sv = st[ss][dd];
      aq += sv * Wq[dd * 64 + e];
      ak += sv * Wk[dd * 64 + e];
      av += sv * Wv[dd * 64 + e];
    }
    qs[ss][e] = aq; ks[ss][e] = ak; vs[ss][e] = av;
  }
  __syncthreads();

  const float scale = 0.125f;
  for (int i = tid; i < 1024; i += 256) {
    int si = i >> 5, tj = i & 31;
    float a = 0.f;
    #pragma unroll 8
    for (int ee = 0; ee < 64; ee++) a += qs[si][ee] * ks[tj][ee];
    at[si][tj] = a * scale;
  }
  __syncthreads();

  if (tid < 32) {
    float m = -1e30f;
    for (int j = 0; j < 32; j++) m = fmaxf(m, at[tid][j]);
    float sum = 0.f;
    for (int j = 0; j < 32; j++) { float ev = __expf(at[tid][j] - m); at[tid][j] = ev; sum += ev; }
    float inv = 1.f / sum;
    for (int j = 0; j < 32; j++) at[tid][j] *= inv;
  }
  __syncthreads();

  for (int ii = 0; ii < 8; ii++) {
    int ss = sgp * 8 + ii;
    float a = 0.f;
    #pragma unroll 8
    for (int tj = 0; tj < 32; tj++) a += at[ss][tj] * vs[tj][e];
    out_tok[(size_t)bh * 2048 + ss * 64 + e] = a;
  }
}

// ---------------------------------------------------------------------------
// Kernel 4: out_x[n, h*64+d] = sum_s w[n,h,s] * out_tok[batch[n],h,s,d]
// ---------------------------------------------------------------------------
__global__ __launch_bounds__(256) void k_gather(
    const float* __restrict__ w, const float* __restrict__ out_tok,
    const int* __restrict__ batch, float* __restrict__ out_x, int N)
{
  __shared__ float w_sh[64][32];
  __shared__ float tok[32][64];
  __shared__ int b_sh[64];
  const int h = blockIdx.y;
  const int n0 = blockIdx.x * 64;
  const int tid = threadIdx.x;
  const int cnt = min(64, N - n0);

  for (int i = tid; i < cnt * 32; i += 256)
    w_sh[i >> 5][i & 31] = w[(size_t)(n0 + (i >> 5)) * (NH * NS) + h * NS + (i & 31)];
  if (tid < cnt) b_sh[tid] = batch[n0 + tid];
  __syncthreads();

  const int d = tid & 63, ng = tid >> 6;
  int i = 0;
  while (i < cnt) {
    int b = b_sh[i];
    int j = i;
    while (j < cnt && b_sh[j] == b) j++;
    __syncthreads();
    for (int t = tid; t < 2048; t += 256)
      tok[t >> 6][t & 63] = out_tok[((size_t)b * NH + h) * 2048 + t];
    __syncthreads();
    for (int r = i + ng; r < j; r += 4) {
      float a = 0.f;
      #pragma unroll 8
      for (int ss = 0; ss < 32; ss++) a += w_sh[r][ss] * tok[ss][d];
      out_x[(size_t)(n0 + r) * INNER + h * ND + d] = a;
    }
    i = j;
  }
}

// ---------------------------------------------------------------------------
extern "C" void kernel_launch(void* const* d_in, const int* in_sizes, int n_in,
                              void* d_out, int out_size, void* d_ws, size_t ws_size,
                              hipStream_t stream) {
  const float* x      = (const float*)d_in[0];
  const int*   batch  = (const int*)d_in[1];
  const float* Wfx    = (const float*)d_in[2];
  const float* bfx    = (const float*)d_in[3];
  const float* Wx     = (const float*)d_in[4];
  const float* bx     = (const float*)d_in[5];
  const float* Wsl    = (const float*)d_in[6];
  const float* bsl    = (const float*)d_in[7];
  const float* gtemp  = (const float*)d_in[8];
  const float* Wq     = (const float*)d_in[9];
  const float* Wk     = (const float*)d_in[10];
  const float* Wv     = (const float*)d_in[11];
  const float* Wout   = (const float*)d_in[12];
  const float* bout   = (const float*)d_in[13];
  float* out = (float*)d_out;

  const int N = in_sizes[0] / NDIM;   // 30000

  float* ws    = (float*)d_ws;
  float* fx    = ws;                              // [N,512]; reused as out_x
  float* w     = fx + (size_t)N * INNER;          // [N,256]
  float* stok  = w + (size_t)N * (NH * NS);       // 131072
  float* snorm = stok + (size_t)NB * NH * NS * ND;
  float* otok  = snorm + (size_t)NB * NH * NS;
  float* bcomb = otok + (size_t)NB * NH * NS * ND;
  short* Bt1h  = (short*)(bcomb + 256);           // [768][256] bf16
  short* Bt1l  = Bt1h + 768 * 256;
  short* Bt2h  = Bt1l + 768 * 256;                // [256][512] bf16
  short* Bt2l  = Bt2h + 256 * 512;

  hipMemsetAsync(stok, 0, (size_t)(NB * NH * NS * ND + NB * NH * NS) * sizeof(float), stream);

  k_prep<<<1281, 256, 0, stream>>>(Wfx, Wx, bx, Wsl, bsl, Wout, Bt1h, Bt1l, Bt2h, Bt2l, bcomb);

  dim3 g1(6, (N + 127) / 128);
  k_fxw<<<g1, 256, 0, stream>>>(x, Bt1h, Bt1l, bfx, bcomb, gtemp, fx, w, N);

  dim3 g2((N + 511) / 512, NH);
  k_scatter<<<g2, 256, 0, stream>>>(fx, w, batch, stok, snorm, N);

  k_attn<<<NB * NH, 256, 0, stream>>>(stok, snorm, Wq, Wk, Wv, otok);

  dim3 g4((N + 63) / 64, NH);
  k_gather<<<g4, 256, 0, stream>>>(w, otok, batch, fx /*out_x*/, N);

  dim3 g5(2, (N + 127) / 128);
  k_out<<<g5, 256, 0, stream>>>(fx, Bt2h, Bt2l, bout, out, N);
}

// Round 3
// 410.507 us; speedup vs baseline: 1.5522x; 1.0337x over previous
//
#include <hip/hip_runtime.h>

#define NDIM 256
#define INNER 512
#define NH 8
#define ND 64
#define NS 32
#define NB 8

typedef __attribute__((ext_vector_type(8))) short short8;   // 8 bf16 = 4 VGPR
typedef __attribute__((ext_vector_type(4))) float f32x4;

static __device__ __forceinline__ short f2bf(float f) {
  unsigned u = __float_as_uint(f);
  unsigned r = (u + 0x7fffu + ((u >> 16) & 1u)) >> 16;
  return (short)r;
}
static __device__ __forceinline__ float bf2f(short s) {
  return __uint_as_float(((unsigned)(unsigned short)s) << 16);
}

// ---------------------------------------------------------------------------
// k_xsplit: x fp32 -> Xh/Xl bf16 hi/lo.  id handles 4 floats.
// ---------------------------------------------------------------------------
__global__ __launch_bounds__(256) void k_xsplit(
    const float* __restrict__ x, short* __restrict__ Xh, short* __restrict__ Xl,
    int total4)
{
  int id = blockIdx.x * 256 + threadIdx.x;
  if (id >= total4) return;
  float4 v = *(const float4*)&x[(size_t)id * 4];
  short h0 = f2bf(v.x), h1 = f2bf(v.y), h2 = f2bf(v.z), h3 = f2bf(v.w);
  short4 hv = make_short4(h0, h1, h2, h3);
  short4 lv = make_short4(f2bf(v.x - bf2f(h0)), f2bf(v.y - bf2f(h1)),
                          f2bf(v.z - bf2f(h2)), f2bf(v.w - bf2f(h3)));
  *(short4*)&Xh[(size_t)id * 4] = hv;
  *(short4*)&Xl[(size_t)id * 4] = lv;
}

// ---------------------------------------------------------------------------
// k_prep: Bt1 [768][256] bf16 hi/lo (rows 0..511 Wfx^T, 512..767 (Wx_h@Wsl)^T),
//         bcomb[256] = bx_h @ Wsl + bsl.
// ---------------------------------------------------------------------------
__global__ __launch_bounds__(256) void k_prep(
    const float* __restrict__ Wfx, const float* __restrict__ Wx,
    const float* __restrict__ bx, const float* __restrict__ Wsl,
    const float* __restrict__ bsl,
    short* __restrict__ Bt1h, short* __restrict__ Bt1l,
    float* __restrict__ bcomb)
{
  int id = blockIdx.x * 256 + threadIdx.x;
  if (id < 131072) {                       // Wfx transpose
    int k = id >> 9, n = id & 511;
    float v = Wfx[k * 512 + n];
    short hi = f2bf(v); short lo = f2bf(v - bf2f(hi));
    Bt1h[n * 256 + k] = hi; Bt1l[n * 256 + k] = lo;
  } else if (id < 196608) {                // Wcomb
    int e = id - 131072;
    int c = e & 255, k = e >> 8;
    int h = c >> 5, s = c & 31;
    float acc = 0.f;
    #pragma unroll 8
    for (int d = 0; d < 64; d++) acc += Wx[k * 512 + h * 64 + d] * Wsl[d * 32 + s];
    short hi = f2bf(acc); short lo = f2bf(acc - bf2f(hi));
    Bt1h[(512 + c) * 256 + k] = hi; Bt1l[(512 + c) * 256 + k] = lo;
  } else if (id < 196864) {                // bcomb
    int c = id - 196608;
    int h = c >> 5, s = c & 31;
    float acc = bsl[s];
    #pragma unroll 8
    for (int d = 0; d < 64; d++) acc += bx[h * 64 + d] * Wsl[d * 32 + s];
    bcomb[c] = acc;
  }
}

// ---------------------------------------------------------------------------
// k_fxw: C[N,768] = x @ Bt1^T, split-3 bf16 MFMA, staging from precomputed
// Xh/Xl (pure int4 copies -- no conversion VALU).
//  ct 0..3 -> fx fp32 (+bfx); ct 4..5 -> logits -> softmax -> w bf16 hi/lo.
// ---------------------------------------------------------------------------
__global__ __launch_bounds__(256) void k_fxw(
    const short* __restrict__ Xh, const short* __restrict__ Xl,
    const short* __restrict__ Bt1h, const short* __restrict__ Bt1l,
    const float* __restrict__ bfx, const float* __restrict__ bcomb,
    const float* __restrict__ gtemp,
    float* __restrict__ fx_out, short* __restrict__ wh_out,
    short* __restrict__ wl_out, int N)
{
  __shared__ short Ah[128][40];
  __shared__ short Al[128][40];
  __shared__ short Bh[128][40];
  __shared__ short Bl[128][40];

  const int ct = blockIdx.x;
  const int row0 = blockIdx.y * 128;
  const int tid = threadIdx.x;
  const int lane = tid & 63, l15 = lane & 15, quad = lane >> 4;
  const int wv = tid >> 6, wm = wv & 1, wn = wv >> 1;
  const int ctbase = ct * 128;

  f32x4 acc[4][4];
  #pragma unroll
  for (int i = 0; i < 4; i++)
    #pragma unroll
    for (int j = 0; j < 4; j++) acc[i][j] = (f32x4){0.f, 0.f, 0.f, 0.f};

  for (int kt = 0; kt < 8; kt++) {       // K=256, BK=32
    #pragma unroll
    for (int t = 0; t < 2; t++) {        // A: 512 int4 chunks per array
      int i = tid + t * 256;
      int row = i >> 2, kc = (i & 3) * 8;
      int gr = row0 + row;
      int4 vh = make_int4(0, 0, 0, 0), vl = make_int4(0, 0, 0, 0);
      if (gr < N) {
        size_t src = (size_t)gr * 256 + kt * 32 + kc;
        vh = *(const int4*)&Xh[src];
        vl = *(const int4*)&Xl[src];
      }
      *(int4*)&Ah[row][kc] = vh;
      *(int4*)&Al[row][kc] = vl;
    }
    #pragma unroll
    for (int t = 0; t < 2; t++) {        // B
      int i = tid + t * 256;
      int row = i >> 2, kc = (i & 3) * 8;
      size_t src = (size_t)(ctbase + row) * 256 + kt * 32 + kc;
      *(int4*)&Bh[row][kc] = *(const int4*)&Bt1h[src];
      *(int4*)&Bl[row][kc] = *(const int4*)&Bt1l[src];
    }
    __syncthreads();

    short8 ah[4], al[4];
    #pragma unroll
    for (int mt = 0; mt < 4; mt++) {
      int m = wm * 64 + mt * 16 + l15;
      ah[mt] = *(const short8*)&Ah[m][quad * 8];
      al[mt] = *(const short8*)&Al[m][quad * 8];
    }
    #pragma unroll
    for (int nt = 0; nt < 4; nt++) {
      int n = wn * 64 + nt * 16 + l15;
      short8 bh = *(const short8*)&Bh[n][quad * 8];
      short8 bl = *(const short8*)&Bl[n][quad * 8];
      #pragma unroll
      for (int mt = 0; mt < 4; mt++) {
        acc[mt][nt] = __builtin_amdgcn_mfma_f32_16x16x32_bf16(ah[mt], bh, acc[mt][nt], 0, 0, 0);
        acc[mt][nt] = __builtin_amdgcn_mfma_f32_16x16x32_bf16(ah[mt], bl, acc[mt][nt], 0, 0, 0);
        acc[mt][nt] = __builtin_amdgcn_mfma_f32_16x16x32_bf16(al[mt], bh, acc[mt][nt], 0, 0, 0);
      }
    }
    __syncthreads();
  }

  if (ct < 4) {
    #pragma unroll
    for (int nt = 0; nt < 4; nt++) {
      int c = ctbase + wn * 64 + nt * 16 + l15;
      float bias = bfx[c];
      #pragma unroll
      for (int mt = 0; mt < 4; mt++)
        #pragma unroll
        for (int r = 0; r < 4; r++) {
          int row = row0 + wm * 64 + mt * 16 + quad * 4 + r;
          if (row < N) fx_out[(size_t)row * INNER + c] = acc[mt][nt][r] + bias;
        }
    }
  } else {
    int ct2 = ct - 4;
    #pragma unroll
    for (int g = 0; g < 2; g++) {
      int lcbase = ct2 * 128 + wn * 64 + g * 32;
      int h = lcbase >> 5;
      float inv_t = 1.0f / gtemp[h];
      int lc0 = lcbase + l15, lc1 = lcbase + 16 + l15;
      float b0 = bcomb[lc0], b1 = bcomb[lc1];
      #pragma unroll
      for (int mt = 0; mt < 4; mt++) {
        #pragma unroll
        for (int r = 0; r < 4; r++) {
          float s0 = (acc[mt][2 * g + 0][r] + b0) * inv_t;
          float s1 = (acc[mt][2 * g + 1][r] + b1) * inv_t;
          float m = fmaxf(s0, s1);
          #pragma unroll
          for (int off = 1; off < 16; off <<= 1) m = fmaxf(m, __shfl_xor(m, off, 16));
          float e0 = __expf(s0 - m), e1 = __expf(s1 - m);
          float sum = e0 + e1;
          #pragma unroll
          for (int off = 1; off < 16; off <<= 1) sum += __shfl_xor(sum, off, 16);
          float inv = 1.0f / sum;
          int row = row0 + wm * 64 + mt * 16 + quad * 4 + r;
          if (row < N) {
            float w0v = e0 * inv, w1v = e1 * inv;
            size_t base = (size_t)row * (NH * NS);
            short h0 = f2bf(w0v), h1 = f2bf(w1v);
            wh_out[base + lc0] = h0; wl_out[base + lc0] = f2bf(w0v - bf2f(h0));
            wh_out[base + lc1] = h1; wl_out[base + lc1] = f2bf(w1v - bf2f(h1));
          }
        }
      }
    }
  }
}

// ---------------------------------------------------------------------------
// k_scatter: slice_token[b,h,s,d] += w*fx ; slice_norm += w.  batch sorted.
// w reconstructed fp32 from hi/lo.
// ---------------------------------------------------------------------------
__global__ __launch_bounds__(256) void k_scatter(
    const float* __restrict__ fx,
    const short* __restrict__ wh, const short* __restrict__ wl,
    const int* __restrict__ batch,
    float* __restrict__ stok, float* __restrict__ snorm, int N)
{
  __shared__ float w_sh[64][32];
  __shared__ float fx_sh[64][64];
  __shared__ int b_sh[64];
  const int h = blockIdx.y;
  const int n0 = blockIdx.x * 512;
  const int tid = threadIdx.x;
  const int d = tid & 63, sg = tid >> 6;
  float acc[8] = {0, 0, 0, 0, 0, 0, 0, 0};
  float nacc = 0.f;
  int cur_b = batch[n0];
  const int nend = min(n0 + 512, N);

  for (int t0 = n0; t0 < nend; t0 += 64) {
    const int cnt = min(64, nend - t0);
    __syncthreads();
    for (int i = tid; i < cnt * 32; i += 256) {
      size_t idx = (size_t)(t0 + (i >> 5)) * (NH * NS) + h * NS + (i & 31);
      w_sh[i >> 5][i & 31] = bf2f(wh[idx]) + bf2f(wl[idx]);
    }
    for (int i = tid; i < cnt * 64; i += 256)
      fx_sh[i >> 6][i & 63] = fx[(size_t)(t0 + (i >> 6)) * INNER + h * ND + (i & 63)];
    if (tid < cnt) b_sh[tid] = batch[t0 + tid];
    __syncthreads();

    for (int r = 0; r < cnt; r++) {
      int bb = b_sh[r];
      if (bb != cur_b) {
        #pragma unroll
        for (int j = 0; j < 8; j++) {
          atomicAdd(&stok[(((size_t)cur_b * NH + h) * NS + sg * 8 + j) * ND + d], acc[j]);
          acc[j] = 0.f;
        }
        if (tid < 32) { atomicAdd(&snorm[((size_t)cur_b * NH + h) * NS + tid], nacc); nacc = 0.f; }
        cur_b = bb;
      }
      const float4* wp = (const float4*)&w_sh[r][sg * 8];
      float4 w0 = wp[0], w1 = wp[1];
      float f = fx_sh[r][d];
      acc[0] += w0.x * f; acc[1] += w0.y * f; acc[2] += w0.z * f; acc[3] += w0.w * f;
      acc[4] += w1.x * f; acc[5] += w1.y * f; acc[6] += w1.z * f; acc[7] += w1.w * f;
      if (tid < 32) nacc += w_sh[r][tid];
    }
  }
  #pragma unroll
  for (int j = 0; j < 8; j++)
    atomicAdd(&stok[(((size_t)cur_b * NH + h) * NS + sg * 8 + j) * ND + d], acc[j]);
  if (tid < 32) atomicAdd(&snorm[((size_t)cur_b * NH + h) * NS + tid], nacc);
}

// ---------------------------------------------------------------------------
// k_attn: per (b,h): normalize tokens, q/k/v, 32x32 attention, out_tok (LDS),
// then P[s][c] = sum_d out_tok[s][d]*Wout[h*64+d][c]; store P^T bf16 hi/lo
// at PT[b][c][h*32+s].
// ---------------------------------------------------------------------------
__global__ __launch_bounds__(256) void k_attn(
    const float* __restrict__ stok, const float* __restrict__ snorm,
    const float* __restrict__ Wq, const float* __restrict__ Wk,
    const float* __restrict__ Wv, const float* __restrict__ Wout,
    short* __restrict__ PTh, short* __restrict__ PTl)
{
  __shared__ float st[32][65];
  __shared__ float qs[32][65];
  __shared__ float ks[32][65];
  __shared__ float vs[32][65];
  __shared__ float at[32][33];
  __shared__ float ot[32][65];
  const int bh = blockIdx.x;
  const int b = bh >> 3, h = bh & 7;
  const int tid = threadIdx.x;

  for (int i = tid; i < 2048; i += 256) {
    int ss = i >> 6;
    float nrm = snorm[(size_t)bh * NS + ss] + 1e-5f;
    st[ss][i & 63] = stok[(size_t)bh * 2048 + i] / nrm;
  }
  __syncthreads();

  const int e = tid & 63, sgp = tid >> 6;
  for (int ii = 0; ii < 8; ii++) {
    int ss = sgp * 8 + ii;
    float aq = 0.f, ak = 0.f, av = 0.f;
    #pragma unroll 8
    for (int dd = 0; dd < 64; dd++) {
      float sv = st[ss][dd];
      aq += sv * Wq[dd * 64 + e];
      ak += sv * Wk[dd * 64 + e];
      av += sv * Wv[dd * 64 + e];
    }
    qs[ss][e] = aq; ks[ss][e] = ak; vs[ss][e] = av;
  }
  __syncthreads();

  const float scale = 0.125f;
  for (int i = tid; i < 1024; i += 256) {
    int si = i >> 5, tj = i & 31;
    float a = 0.f;
    #pragma unroll 8
    for (int ee = 0; ee < 64; ee++) a += qs[si][ee] * ks[tj][ee];
    at[si][tj] = a * scale;
  }
  __syncthreads();

  if (tid < 32) {
    float m = -1e30f;
    for (int j = 0; j < 32; j++) m = fmaxf(m, at[tid][j]);
    float sum = 0.f;
    for (int j = 0; j < 32; j++) { float ev = __expf(at[tid][j] - m); at[tid][j] = ev; sum += ev; }
    float inv = 1.f / sum;
    for (int j = 0; j < 32; j++) at[tid][j] *= inv;
  }
  __syncthreads();

  for (int ii = 0; ii < 8; ii++) {
    int ss = sgp * 8 + ii;
    float a = 0.f;
    #pragma unroll 8
    for (int tj = 0; tj < 32; tj++) a += at[ss][tj] * vs[tj][e];
    ot[ss][e] = a;
  }
  __syncthreads();

  // P-phase: thread -> (s = tid>>3, 32 cols starting (tid&7)*32)
  const int s_p = tid >> 3;
  const int c0 = (tid & 7) * 32;
  float pacc[32];
  #pragma unroll
  for (int q = 0; q < 32; q++) pacc[q] = 0.f;
  for (int dd = 0; dd < 64; dd++) {
    float o = ot[s_p][dd];
    const float4* wr = (const float4*)&Wout[(size_t)(h * 64 + dd) * NDIM + c0];
    #pragma unroll
    for (int q = 0; q < 8; q++) {
      float4 v = wr[q];
      pacc[4 * q + 0] += o * v.x;
      pacc[4 * q + 1] += o * v.y;
      pacc[4 * q + 2] += o * v.z;
      pacc[4 * q + 3] += o * v.w;
    }
  }
  #pragma unroll
  for (int q = 0; q < 32; q++) {
    int c = c0 + q;
    float val = pacc[q];
    short hi = f2bf(val);
    size_t dst = ((size_t)b * NDIM + c) * 256 + h * 32 + s_p;
    PTh[dst] = hi;
    PTl[dst] = f2bf(val - bf2f(hi));
  }
}

// ---------------------------------------------------------------------------
// k_outw: out[n,c] = sum_{hs} w[n,hs] * PT[batch[n]][c][hs] + bout[c].
// Fuses gather + out-GEMM. Split-3 bf16 MFMA; per-128-row tile, iterate
// graph segments with zero-masked A staging (each row in exactly 1 segment).
// ---------------------------------------------------------------------------
__global__ __launch_bounds__(256) void k_outw(
    const short* __restrict__ wh, const short* __restrict__ wl,
    const short* __restrict__ PTh, const short* __restrict__ PTl,
    const int* __restrict__ batch, const float* __restrict__ bout,
    float* __restrict__ out, int N)
{
  __shared__ short Ah[128][40];
  __shared__ short Al[128][40];
  __shared__ short Bh[128][40];
  __shared__ short Bl[128][40];
  __shared__ int b_sh[128];

  const int ct = blockIdx.x;           // 0..1
  const int row0 = blockIdx.y * 128;
  const int tid = threadIdx.x;
  const int lane = tid & 63, l15 = lane & 15, quad = lane >> 4;
  const int wv = tid >> 6, wm = wv & 1, wn = wv >> 1;
  const int ctbase = ct * 128;
  const int cnt = min(128, N - row0);

  if (tid < 128) b_sh[tid] = (tid < cnt) ? batch[row0 + tid] : -1;
  __syncthreads();

  f32x4 acc[4][4];
  #pragma unroll
  for (int i = 0; i < 4; i++)
    #pragma unroll
    for (int j = 0; j < 4; j++) acc[i][j] = (f32x4){0.f, 0.f, 0.f, 0.f};

  int i0 = 0;
  while (i0 < cnt) {
    int b = b_sh[i0];
    int j = i0;
    while (j < cnt && b_sh[j] == b) j++;   // uniform scan

    for (int kt = 0; kt < 8; kt++) {
      #pragma unroll
      for (int t = 0; t < 2; t++) {        // A: w rows masked to [i0,j)
        int i = tid + t * 256;
        int row = i >> 2, kc = (i & 3) * 8;
        int4 vh = make_int4(0, 0, 0, 0), vl = make_int4(0, 0, 0, 0);
        if (row >= i0 && row < j) {
          size_t src = (size_t)(row0 + row) * 256 + kt * 32 + kc;
          vh = *(const int4*)&wh[src];
          vl = *(const int4*)&wl[src];
        }
        *(int4*)&Ah[row][kc] = vh;
        *(int4*)&Al[row][kc] = vl;
      }
      #pragma unroll
      for (int t = 0; t < 2; t++) {        // B from PT[b]
        int i = tid + t * 256;
        int row = i >> 2, kc = (i & 3) * 8;
        size_t src = ((size_t)b * NDIM + ctbase + row) * 256 + kt * 32 + kc;
        *(int4*)&Bh[row][kc] = *(const int4*)&PTh[src];
        *(int4*)&Bl[row][kc] = *(const int4*)&PTl[src];
      }
      __syncthreads();

      short8 ah[4], al[4];
      #pragma unroll
      for (int mt = 0; mt < 4; mt++) {
        int m = wm * 64 + mt * 16 + l15;
        ah[mt] = *(const short8*)&Ah[m][quad * 8];
        al[mt] = *(const short8*)&Al[m][quad * 8];
      }
      #pragma unroll
      for (int nt = 0; nt < 4; nt++) {
        int n = wn * 64 + nt * 16 + l15;
        short8 bh = *(const short8*)&Bh[n][quad * 8];
        short8 bl = *(const short8*)&Bl[n][quad * 8];
        #pragma unroll
        for (int mt = 0; mt < 4; mt++) {
          acc[mt][nt] = __builtin_amdgcn_mfma_f32_16x16x32_bf16(ah[mt], bh, acc[mt][nt], 0, 0, 0);
          acc[mt][nt] = __builtin_amdgcn_mfma_f32_16x16x32_bf16(ah[mt], bl, acc[mt][nt], 0, 0, 0);
          acc[mt][nt] = __builtin_amdgcn_mfma_f32_16x16x32_bf16(al[mt], bh, acc[mt][nt], 0, 0, 0);
        }
      }
      __syncthreads();
    }
    i0 = j;
  }

  #pragma unroll
  for (int nt = 0; nt < 4; nt++) {
    int c = ctbase + wn * 64 + nt * 16 + l15;
    float bias = bout[c];
    #pragma unroll
    for (int mt = 0; mt < 4; mt++)
      #pragma unroll
      for (int r = 0; r < 4; r++) {
        int row = row0 + wm * 64 + mt * 16 + quad * 4 + r;
        if (row < N) out[(size_t)row * NDIM + c] = acc[mt][nt][r] + bias;
      }
  }
}

// ---------------------------------------------------------------------------
extern "C" void kernel_launch(void* const* d_in, const int* in_sizes, int n_in,
                              void* d_out, int out_size, void* d_ws, size_t ws_size,
                              hipStream_t stream) {
  const float* x      = (const float*)d_in[0];
  const int*   batch  = (const int*)d_in[1];
  const float* Wfx    = (const float*)d_in[2];
  const float* bfx    = (const float*)d_in[3];
  const float* Wx     = (const float*)d_in[4];
  const float* bx     = (const float*)d_in[5];
  const float* Wsl    = (const float*)d_in[6];
  const float* bsl    = (const float*)d_in[7];
  const float* gtemp  = (const float*)d_in[8];
  const float* Wq     = (const float*)d_in[9];
  const float* Wk     = (const float*)d_in[10];
  const float* Wv     = (const float*)d_in[11];
  const float* Wout   = (const float*)d_in[12];
  const float* bout   = (const float*)d_in[13];
  float* out = (float*)d_out;

  const int N = in_sizes[0] / NDIM;   // 30000

  float* ws    = (float*)d_ws;
  float* fx    = ws;                               // [N,512] fp32
  float* stok  = fx + (size_t)N * INNER;           // 131072
  float* snorm = stok + (size_t)NB * NH * NS * ND; // 2048
  float* bcomb = snorm + (size_t)NB * NH * NS;     // 256
  short* Bt1h  = (short*)(bcomb + 256);            // [768][256]
  short* Bt1l  = Bt1h + 768 * 256;
  short* Xh    = Bt1l + 768 * 256;                 // [N][256]
  short* Xl    = Xh + (size_t)N * 256;
  short* whb   = Xl + (size_t)N * 256;             // [N][256]
  short* wlb   = whb + (size_t)N * 256;
  short* PTh   = wlb + (size_t)N * 256;            // [B][256][256]
  short* PTl   = PTh + (size_t)NB * 256 * 256;

  hipMemsetAsync(stok, 0, (size_t)(NB * NH * NS * ND + NB * NH * NS) * sizeof(float), stream);

  k_xsplit<<<(N * 64 + 255) / 256, 256, 0, stream>>>(x, Xh, Xl, N * 64);

  k_prep<<<769, 256, 0, stream>>>(Wfx, Wx, bx, Wsl, bsl, Bt1h, Bt1l, bcomb);

  dim3 g1(6, (N + 127) / 128);
  k_fxw<<<g1, 256, 0, stream>>>(Xh, Xl, Bt1h, Bt1l, bfx, bcomb, gtemp, fx, whb, wlb, N);

  dim3 g2((N + 511) / 512, NH);
  k_scatter<<<g2, 256, 0, stream>>>(fx, whb, wlb, batch, stok, snorm, N);

  k_attn<<<NB * NH, 256, 0, stream>>>(stok, snorm, Wq, Wk, Wv, Wout, PTh, PTl);

  dim3 g5(2, (N + 127) / 128);
  k_outw<<<g5, 256, 0, stream>>>(whb, wlb, PTh, PTl, batch, bout, out, N);
}

// Round 5
// 387.738 us; speedup vs baseline: 1.6433x; 1.0587x over previous
//
#include <hip/hip_runtime.h>

#define NDIM 256
#define INNER 512
#define NH 8
#define ND 64
#define NS 32
#define NB 8
#define NP 30208   // padded node count (multiple of 128, covers N + chunk overrun)

typedef __attribute__((ext_vector_type(8))) short short8;   // 8 bf16 = 4 VGPR
typedef __attribute__((ext_vector_type(4))) float f32x4;

static __device__ __forceinline__ short f2bf(float f) {
  unsigned u = __float_as_uint(f);
  unsigned r = (u + 0x7fffu + ((u >> 16) & 1u)) >> 16;
  return (short)r;
}
static __device__ __forceinline__ float bf2f(short s) {
  return __uint_as_float(((unsigned)(unsigned short)s) << 16);
}

// ---------------------------------------------------------------------------
// k_xsplit: x fp32 -> Xh/Xl bf16 hi/lo.
// ---------------------------------------------------------------------------
__global__ __launch_bounds__(256) void k_xsplit(
    const float* __restrict__ x, short* __restrict__ Xh, short* __restrict__ Xl,
    int total4)
{
  int id = blockIdx.x * 256 + threadIdx.x;
  if (id >= total4) return;
  float4 v = *(const float4*)&x[(size_t)id * 4];
  short h0 = f2bf(v.x), h1 = f2bf(v.y), h2 = f2bf(v.z), h3 = f2bf(v.w);
  short4 hv = make_short4(h0, h1, h2, h3);
  short4 lv = make_short4(f2bf(v.x - bf2f(h0)), f2bf(v.y - bf2f(h1)),
                          f2bf(v.z - bf2f(h2)), f2bf(v.w - bf2f(h3)));
  *(short4*)&Xh[(size_t)id * 4] = hv;
  *(short4*)&Xl[(size_t)id * 4] = lv;
}

// ---------------------------------------------------------------------------
// k_prep: Bt1 [768][256] bf16 hi/lo (rows 0..511 Wfx^T, 512..767 (Wx_h@Wsl)^T),
//         bcomb[256] = bx_h @ Wsl + bsl.
// ---------------------------------------------------------------------------
__global__ __launch_bounds__(256) void k_prep(
    const float* __restrict__ Wfx, const float* __restrict__ Wx,
    const float* __restrict__ bx, const float* __restrict__ Wsl,
    const float* __restrict__ bsl,
    short* __restrict__ Bt1h, short* __restrict__ Bt1l,
    float* __restrict__ bcomb)
{
  int id = blockIdx.x * 256 + threadIdx.x;
  if (id < 131072) {
    int k = id >> 9, n = id & 511;
    float v = Wfx[k * 512 + n];
    short hi = f2bf(v); short lo = f2bf(v - bf2f(hi));
    Bt1h[n * 256 + k] = hi; Bt1l[n * 256 + k] = lo;
  } else if (id < 196608) {
    int e = id - 131072;
    int c = e & 255, k = e >> 8;
    int h = c >> 5, s = c & 31;
    float acc = 0.f;
    #pragma unroll 8
    for (int d = 0; d < 64; d++) acc += Wx[k * 512 + h * 64 + d] * Wsl[d * 32 + s];
    short hi = f2bf(acc); short lo = f2bf(acc - bf2f(hi));
    Bt1h[(512 + c) * 256 + k] = hi; Bt1l[(512 + c) * 256 + k] = lo;
  } else if (id < 196864) {
    int c = id - 196608;
    int h = c >> 5, s = c & 31;
    float acc = bsl[s];
    #pragma unroll 8
    for (int d = 0; d < 64; d++) acc += bx[h * 64 + d] * Wsl[d * 32 + s];
    bcomb[c] = acc;
  }
}

// ---------------------------------------------------------------------------
// k_segs: seg[b] = first node index with batch >= b (batch sorted). seg[8]=N.
// ---------------------------------------------------------------------------
__global__ __launch_bounds__(256) void k_segs(
    const int* __restrict__ batch, int* __restrict__ seg, int N)
{
  int tid = threadIdx.x;
  if (tid <= 8) seg[tid] = (tid == 0) ? 0 : N;
  __syncthreads();
  for (int i = tid; i < N; i += 256) {
    int b = batch[i];
    int p = (i == 0) ? -1 : batch[i - 1];
    if (p < b) {
      for (int v = p + 1; v <= b; v++)
        if (v >= 1) atomicMin(&seg[v], i);
    }
  }
}

// ---------------------------------------------------------------------------
// k_fxw: C[N,768] = x @ Bt1^T, split-3 bf16 MFMA.
//  ct 0..3 -> fx cols: LDS-transposed and stored as fxT bf16 hi/lo [512][NP]
//  ct 4..5 -> logits -> tempered softmax -> w bf16 hi/lo [n][256]
// ---------------------------------------------------------------------------
__global__ __launch_bounds__(256) void k_fxw(
    const short* __restrict__ Xh, const short* __restrict__ Xl,
    const short* __restrict__ Bt1h, const short* __restrict__ Bt1l,
    const float* __restrict__ bfx, const float* __restrict__ bcomb,
    const float* __restrict__ gtemp,
    short* __restrict__ fxTh, short* __restrict__ fxTl,
    short* __restrict__ wh_out, short* __restrict__ wl_out, int N)
{
  __shared__ __align__(16) short smem[20480];     // 40 KB
  short (*Ah)[40] = (short(*)[40])&smem[0];
  short (*Al)[40] = (short(*)[40])&smem[5120];
  short (*Bh)[40] = (short(*)[40])&smem[10240];
  short (*Bl)[40] = (short(*)[40])&smem[15360];

  const int ct = blockIdx.x;
  const int row0 = blockIdx.y * 128;
  const int tid = threadIdx.x;
  const int lane = tid & 63, l15 = lane & 15, quad = lane >> 4;
  const int wv = tid >> 6, wm = wv & 1, wn = wv >> 1;
  const int ctbase = ct * 128;

  f32x4 acc[4][4];
  #pragma unroll
  for (int i = 0; i < 4; i++)
    #pragma unroll
    for (int j = 0; j < 4; j++) acc[i][j] = (f32x4){0.f, 0.f, 0.f, 0.f};

  for (int kt = 0; kt < 8; kt++) {       // K=256, BK=32
    #pragma unroll
    for (int t = 0; t < 2; t++) {        // A (x tile): 512 int4 chunks/array
      int i = tid + t * 256;
      int row = i >> 2, kc = (i & 3) * 8;
      int gr = row0 + row;
      int4 vh = make_int4(0, 0, 0, 0), vl = make_int4(0, 0, 0, 0);
      if (gr < N) {
        size_t src = (size_t)gr * 256 + kt * 32 + kc;
        vh = *(const int4*)&Xh[src];
        vl = *(const int4*)&Xl[src];
      }
      *(int4*)&Ah[row][kc] = vh;
      *(int4*)&Al[row][kc] = vl;
    }
    #pragma unroll
    for (int t = 0; t < 2; t++) {        // B (weights)
      int i = tid + t * 256;
      int row = i >> 2, kc = (i & 3) * 8;
      size_t src = (size_t)(ctbase + row) * 256 + kt * 32 + kc;
      *(int4*)&Bh[row][kc] = *(const int4*)&Bt1h[src];
      *(int4*)&Bl[row][kc] = *(const int4*)&Bt1l[src];
    }
    __syncthreads();

    short8 ah[4], al[4];
    #pragma unroll
    for (int mt = 0; mt < 4; mt++) {
      int m = wm * 64 + mt * 16 + l15;
      ah[mt] = *(const short8*)&Ah[m][quad * 8];
      al[mt] = *(const short8*)&Al[m][quad * 8];
    }
    #pragma unroll
    for (int nt = 0; nt < 4; nt++) {
      int n = wn * 64 + nt * 16 + l15;
      short8 bh = *(const short8*)&Bh[n][quad * 8];
      short8 bl = *(const short8*)&Bl[n][quad * 8];
      #pragma unroll
      for (int mt = 0; mt < 4; mt++) {
        acc[mt][nt] = __builtin_amdgcn_mfma_f32_16x16x32_bf16(ah[mt], bh, acc[mt][nt], 0, 0, 0);
        acc[mt][nt] = __builtin_amdgcn_mfma_f32_16x16x32_bf16(ah[mt], bl, acc[mt][nt], 0, 0, 0);
        acc[mt][nt] = __builtin_amdgcn_mfma_f32_16x16x32_bf16(al[mt], bh, acc[mt][nt], 0, 0, 0);
      }
    }
    __syncthreads();
  }

  if (ct < 4) {
    // two-pass LDS transpose -> fxT[c][n] bf16 hi (pass 0) / lo (pass 1)
    short (*T)[136] = (short(*)[136])&smem[0];   // 128 x 136
    #pragma unroll
    for (int pass = 0; pass < 2; pass++) {
      __syncthreads();
      #pragma unroll
      for (int nt = 0; nt < 4; nt++) {
        int cl = wn * 64 + nt * 16 + l15;
        float bias = bfx[ctbase + cl];
        #pragma unroll
        for (int mt = 0; mt < 4; mt++)
          #pragma unroll
          for (int r = 0; r < 4; r++) {
            int rl = wm * 64 + mt * 16 + quad * 4 + r;
            float v = acc[mt][nt][r] + bias;
            short hi2 = f2bf(v);
            T[cl][rl] = pass ? f2bf(v - bf2f(hi2)) : hi2;
          }
      }
      __syncthreads();
      short* dst = pass ? fxTl : fxTh;
      #pragma unroll
      for (int t = 0; t < 8; t++) {
        int idx = tid + t * 256;                 // 2048 int4 chunks
        int row = idx >> 4, kc = (idx & 15) * 8;
        *(int4*)&dst[(size_t)(ctbase + row) * NP + row0 + kc] = *(const int4*)&T[row][kc];
      }
    }
  } else {
    int ct2 = ct - 4;
    #pragma unroll
    for (int g = 0; g < 2; g++) {
      int lcbase = ct2 * 128 + wn * 64 + g * 32;
      int h = lcbase >> 5;
      float inv_t = 1.0f / gtemp[h];
      int lc0 = lcbase + l15, lc1 = lcbase + 16 + l15;
      float b0 = bcomb[lc0], b1 = bcomb[lc1];
      #pragma unroll
      for (int mt = 0; mt < 4; mt++) {
        #pragma unroll
        for (int r = 0; r < 4; r++) {
          float s0 = (acc[mt][2 * g + 0][r] + b0) * inv_t;
          float s1 = (acc[mt][2 * g + 1][r] + b1) * inv_t;
          float m = fmaxf(s0, s1);
          #pragma unroll
          for (int off = 1; off < 16; off <<= 1) m = fmaxf(m, __shfl_xor(m, off, 16));
          float e0 = __expf(s0 - m), e1 = __expf(s1 - m);
          float sum = e0 + e1;
          #pragma unroll
          for (int off = 1; off < 16; off <<= 1) sum += __shfl_xor(sum, off, 16);
          float inv = 1.0f / sum;
          int row = row0 + wm * 64 + mt * 16 + quad * 4 + r;
          if (row < N) {
            float w0v = e0 * inv, w1v = e1 * inv;
            size_t base = (size_t)row * (NH * NS);
            short h0 = f2bf(w0v), h1 = f2bf(w1v);
            wh_out[base + lc0] = h0; wl_out[base + lc0] = f2bf(w0v - bf2f(h0));
            wh_out[base + lc1] = h1; wl_out[base + lc1] = f2bf(w1v - bf2f(h1));
          }
        }
      }
    }
  }
}

// ---------------------------------------------------------------------------
// k_scat: slice_token[b,h,s,d] = sum_n w[n,hs]*fx[n,hd] via split-3 MFMA over
// K=nodes; slice_norm accumulated from staged w tiles. Per-segment atomic
// flush. Grid (ceil(N/512), NH), 256 threads = 4 waves (each owns 16 d-cols).
// ---------------------------------------------------------------------------
__global__ __launch_bounds__(256) void k_scat(
    const short* __restrict__ wh, const short* __restrict__ wl,
    const short* __restrict__ fxTh, const short* __restrict__ fxTl,
    const int* __restrict__ seg,
    float* __restrict__ stok, float* __restrict__ snorm, int N)
{
  __shared__ short wsh[128][40];     // [n][s]
  __shared__ short wsl[128][40];
  __shared__ short fh[64][136];      // [d][n]
  __shared__ short fl[64][136];
  __shared__ float ln[32];

  const int h = blockIdx.y;
  const int n0 = blockIdx.x * 512;
  const int tid = threadIdx.x;
  const int lane = tid & 63, l15 = lane & 15, quad = lane >> 4;
  const int wv = tid >> 6;                    // d-group: cols wv*16..wv*16+15
  const int nend = min(n0 + 512, N);

  f32x4 acc0 = (f32x4){0.f, 0.f, 0.f, 0.f};   // s rows 0..15
  f32x4 acc1 = (f32x4){0.f, 0.f, 0.f, 0.f};   // s rows 16..31

  for (int b = 0; b < NB; b++) {
    int lo = max(seg[b], n0), hi = min(seg[b + 1], nend);
    if (lo >= hi) continue;
    if (tid < 32) ln[tid] = 0.f;
    int c0lo = (lo - n0) & ~127;
    int c0hi = hi - n0;
    for (int c0 = c0lo; c0 < c0hi; c0 += 128) {
      __syncthreads();
      #pragma unroll
      for (int t = 0; t < 2; t++) {           // stage w rows (128 x 32)
        int idx = tid + t * 256;              // 512 int4 chunks per array
        int row = idx >> 2, kc = (idx & 3) * 8;   // FIX: was idx>>1/(idx&1)*16
        size_t src = (size_t)(n0 + c0 + row) * 256 + h * 32 + kc;
        *(int4*)&wsh[row][kc] = *(const int4*)&wh[src];
        *(int4*)&wsl[row][kc] = *(const int4*)&wl[src];
      }
      #pragma unroll
      for (int t = 0; t < 4; t++) {           // stage fxT rows (64 d x 128 n)
        int idx = tid + t * 256;
        int row = idx >> 4, kc = (idx & 15) * 8;
        size_t src = (size_t)(h * 64 + row) * NP + n0 + c0 + kc;
        *(int4*)&fh[row][kc] = *(const int4*)&fxTh[src];
        *(int4*)&fl[row][kc] = *(const int4*)&fxTl[src];
      }
      __syncthreads();

      { // snorm partial accumulation (hi+lo), masked to segment
        int s = tid >> 3, g = tid & 7;
        float sum = 0.f;
        #pragma unroll
        for (int i2 = 0; i2 < 16; i2++) {
          int nl = g * 16 + i2;
          int ng = n0 + c0 + nl;
          if (ng >= lo && ng < hi)
            sum += bf2f(wsh[nl][s]) + bf2f(wsl[nl][s]);
        }
        atomicAdd(&ln[s], sum);
      }

      for (int k0 = 0; k0 < 128; k0 += 32) {
        int gbase = n0 + c0 + k0;
        if (gbase + 32 <= lo || gbase >= hi) continue;
        bool full = (gbase >= lo) && (gbase + 32 <= hi);
        short8 a0h, a0l, a1h, a1l;
        #pragma unroll
        for (int j = 0; j < 8; j++) {
          int kk = k0 + quad * 8 + j;
          int ng = n0 + c0 + kk;
          bool in = full || (ng >= lo && ng < hi);
          a0h[j] = in ? wsh[kk][l15] : (short)0;
          a0l[j] = in ? wsl[kk][l15] : (short)0;
          a1h[j] = in ? wsh[kk][16 + l15] : (short)0;
          a1l[j] = in ? wsl[kk][16 + l15] : (short)0;
        }
        short8 bh = *(const short8*)&fh[wv * 16 + l15][k0 + quad * 8];
        short8 bl = *(const short8*)&fl[wv * 16 + l15][k0 + quad * 8];
        acc0 = __builtin_amdgcn_mfma_f32_16x16x32_bf16(a0h, bh, acc0, 0, 0, 0);
        acc0 = __builtin_amdgcn_mfma_f32_16x16x32_bf16(a0h, bl, acc0, 0, 0, 0);
        acc0 = __builtin_amdgcn_mfma_f32_16x16x32_bf16(a0l, bh, acc0, 0, 0, 0);
        acc1 = __builtin_amdgcn_mfma_f32_16x16x32_bf16(a1h, bh, acc1, 0, 0, 0);
        acc1 = __builtin_amdgcn_mfma_f32_16x16x32_bf16(a1h, bl, acc1, 0, 0, 0);
        acc1 = __builtin_amdgcn_mfma_f32_16x16x32_bf16(a1l, bh, acc1, 0, 0, 0);
      }
    }
    // flush segment b
    __syncthreads();
    size_t base = ((size_t)b * NH + h) * NS;
    #pragma unroll
    for (int r = 0; r < 4; r++) {
      atomicAdd(&stok[(base + quad * 4 + r) * ND + wv * 16 + l15], acc0[r]);
      atomicAdd(&stok[(base + 16 + quad * 4 + r) * ND + wv * 16 + l15], acc1[r]);
    }
    if (tid < 32) atomicAdd(&snorm[base + tid], ln[tid]);
    acc0 = (f32x4){0.f, 0.f, 0.f, 0.f};
    acc1 = (f32x4){0.f, 0.f, 0.f, 0.f};
    __syncthreads();
  }
}

// ---------------------------------------------------------------------------
// k_attn: per (b,h): normalize tokens, q/k/v, 32x32 attention, out_tok (LDS),
// then P[s][c] = sum_d out_tok[s][d]*Wout[h*64+d][c]; store P^T bf16 hi/lo.
// ---------------------------------------------------------------------------
__global__ __launch_bounds__(256) void k_attn(
    const float* __restrict__ stok, const float* __restrict__ snorm,
    const float* __restrict__ Wq, const float* __restrict__ Wk,
    const float* __restrict__ Wv, const float* __restrict__ Wout,
    short* __restrict__ PTh, short* __restrict__ PTl)
{
  __shared__ float st[32][65];
  __shared__ float qs[32][65];
  __shared__ float ks[32][65];
  __shared__ float vs[32][65];
  __shared__ float at[32][33];
  __shared__ float ot[32][65];
  const int bh = blockIdx.x;
  const int b = bh >> 3, h = bh & 7;
  const int tid = threadIdx.x;

  for (int i = tid; i < 2048; i += 256) {
    int ss = i >> 6;
    float nrm = snorm[(size_t)bh * NS + ss] + 1e-5f;
    st[ss][i & 63] = stok[(size_t)bh * 2048 + i] / nrm;
  }
  __syncthreads();

  const int e = tid & 63, sgp = tid >> 6;
  for (int ii = 0; ii < 8; ii++) {
    int ss = sgp * 8 + ii;
    float aq = 0.f, ak = 0.f, av = 0.f;
    #pragma unroll 8
    for (int dd = 0; dd < 64; dd++) {
      float sv = st[ss][dd];
      aq += sv * Wq[dd * 64 + e];
      ak += sv * Wk[dd * 64 + e];
      av += sv * Wv[dd * 64 + e];
    }
    qs[ss][e] = aq; ks[ss][e] = ak; vs[ss][e] = av;
  }
  __syncthreads();

  const float scale = 0.125f;
  for (int i = tid; i < 1024; i += 256) {
    int si = i >> 5, tj = i & 31;
    float a = 0.f;
    #pragma unroll 8
    for (int ee = 0; ee < 64; ee++) a += qs[si][ee] * ks[tj][ee];
    at[si][tj] = a * scale;
  }
  __syncthreads();

  if (tid < 32) {
    float m = -1e30f;
    for (int j = 0; j < 32; j++) m = fmaxf(m, at[tid][j]);
    float sum = 0.f;
    for (int j = 0; j < 32; j++) { float ev = __expf(at[tid][j] - m); at[tid][j] = ev; sum += ev; }
    float inv = 1.f / sum;
    for (int j = 0; j < 32; j++) at[tid][j] *= inv;
  }
  __syncthreads();

  for (int ii = 0; ii < 8; ii++) {
    int ss = sgp * 8 + ii;
    float a = 0.f;
    #pragma unroll 8
    for (int tj = 0; tj < 32; tj++) a += at[ss][tj] * vs[tj][e];
    ot[ss][e] = a;
  }
  __syncthreads();

  const int s_p = tid >> 3;
  const int c0 = (tid & 7) * 32;
  float pacc[32];
  #pragma unroll
  for (int q = 0; q < 32; q++) pacc[q] = 0.f;
  for (int dd = 0; dd < 64; dd++) {
    float o = ot[s_p][dd];
    const float4* wr = (const float4*)&Wout[(size_t)(h * 64 + dd) * NDIM + c0];
    #pragma unroll
    for (int q = 0; q < 8; q++) {
      float4 v = wr[q];
      pacc[4 * q + 0] += o * v.x;
      pacc[4 * q + 1] += o * v.y;
      pacc[4 * q + 2] += o * v.z;
      pacc[4 * q + 3] += o * v.w;
    }
  }
  #pragma unroll
  for (int q = 0; q < 32; q++) {
    int c = c0 + q;
    float val = pacc[q];
    short hi = f2bf(val);
    size_t dst = ((size_t)b * NDIM + c) * 256 + h * 32 + s_p;
    PTh[dst] = hi;
    PTl[dst] = f2bf(val - bf2f(hi));
  }
}

// ---------------------------------------------------------------------------
// k_outw: out[n,c] = sum_{hs} w[n,hs] * PT[batch[n]][c][hs] + bout[c].
// ---------------------------------------------------------------------------
__global__ __launch_bounds__(256) void k_outw(
    const short* __restrict__ wh, const short* __restrict__ wl,
    const short* __restrict__ PTh, const short* __restrict__ PTl,
    const int* __restrict__ batch, const float* __restrict__ bout,
    float* __restrict__ out, int N)
{
  __shared__ short Ah[128][40];
  __shared__ short Al[128][40];
  __shared__ short Bh[128][40];
  __shared__ short Bl[128][40];
  __shared__ int b_sh[128];

  const int ct = blockIdx.x;
  const int row0 = blockIdx.y * 128;
  const int tid = threadIdx.x;
  const int lane = tid & 63, l15 = lane & 15, quad = lane >> 4;
  const int wv = tid >> 6, wm = wv & 1, wn = wv >> 1;
  const int ctbase = ct * 128;
  const int cnt = min(128, N - row0);

  if (tid < 128) b_sh[tid] = (tid < cnt) ? batch[row0 + tid] : -1;
  __syncthreads();

  f32x4 acc[4][4];
  #pragma unroll
  for (int i = 0; i < 4; i++)
    #pragma unroll
    for (int j = 0; j < 4; j++) acc[i][j] = (f32x4){0.f, 0.f, 0.f, 0.f};

  int i0 = 0;
  while (i0 < cnt) {
    int b = b_sh[i0];
    int j = i0;
    while (j < cnt && b_sh[j] == b) j++;

    for (int kt = 0; kt < 8; kt++) {
      #pragma unroll
      for (int t = 0; t < 2; t++) {
        int i = tid + t * 256;
        int row = i >> 2, kc = (i & 3) * 8;
        int4 vh = make_int4(0, 0, 0, 0), vl = make_int4(0, 0, 0, 0);
        if (row >= i0 && row < j) {
          size_t src = (size_t)(row0 + row) * 256 + kt * 32 + kc;
          vh = *(const int4*)&wh[src];
          vl = *(const int4*)&wl[src];
        }
        *(int4*)&Ah[row][kc] = vh;
        *(int4*)&Al[row][kc] = vl;
      }
      #pragma unroll
      for (int t = 0; t < 2; t++) {
        int i = tid + t * 256;
        int row = i >> 2, kc = (i & 3) * 8;
        size_t src = ((size_t)b * NDIM + ctbase + row) * 256 + kt * 32 + kc;
        *(int4*)&Bh[row][kc] = *(const int4*)&PTh[src];
        *(int4*)&Bl[row][kc] = *(const int4*)&PTl[src];
      }
      __syncthreads();

      short8 ah[4], al[4];
      #pragma unroll
      for (int mt = 0; mt < 4; mt++) {
        int m = wm * 64 + mt * 16 + l15;
        ah[mt] = *(const short8*)&Ah[m][quad * 8];
        al[mt] = *(const short8*)&Al[m][quad * 8];
      }
      #pragma unroll
      for (int nt = 0; nt < 4; nt++) {
        int n = wn * 64 + nt * 16 + l15;
        short8 bh = *(const short8*)&Bh[n][quad * 8];
        short8 bl = *(const short8*)&Bl[n][quad * 8];
        #pragma unroll
        for (int mt = 0; mt < 4; mt++) {
          acc[mt][nt] = __builtin_amdgcn_mfma_f32_16x16x32_bf16(ah[mt], bh, acc[mt][nt], 0, 0, 0);
          acc[mt][nt] = __builtin_amdgcn_mfma_f32_16x16x32_bf16(ah[mt], bl, acc[mt][nt], 0, 0, 0);
          acc[mt][nt] = __builtin_amdgcn_mfma_f32_16x16x32_bf16(al[mt], bh, acc[mt][nt], 0, 0, 0);
        }
      }
      __syncthreads();
    }
    i0 = j;
  }

  #pragma unroll
  for (int nt = 0; nt < 4; nt++) {
    int c = ctbase + wn * 64 + nt * 16 + l15;
    float bias = bout[c];
    #pragma unroll
    for (int mt = 0; mt < 4; mt++)
      #pragma unroll
      for (int r = 0; r < 4; r++) {
        int row = row0 + wm * 64 + mt * 16 + quad * 4 + r;
        if (row < N) out[(size_t)row * NDIM + c] = acc[mt][nt][r] + bias;
      }
  }
}

// ---------------------------------------------------------------------------
extern "C" void kernel_launch(void* const* d_in, const int* in_sizes, int n_in,
                              void* d_out, int out_size, void* d_ws, size_t ws_size,
                              hipStream_t stream) {
  const float* x      = (const float*)d_in[0];
  const int*   batch  = (const int*)d_in[1];
  const float* Wfx    = (const float*)d_in[2];
  const float* bfx    = (const float*)d_in[3];
  const float* Wx     = (const float*)d_in[4];
  const float* bx     = (const float*)d_in[5];
  const float* Wsl    = (const float*)d_in[6];
  const float* bsl    = (const float*)d_in[7];
  const float* gtemp  = (const float*)d_in[8];
  const float* Wq     = (const float*)d_in[9];
  const float* Wk     = (const float*)d_in[10];
  const float* Wv     = (const float*)d_in[11];
  const float* Wout   = (const float*)d_in[12];
  const float* bout   = (const float*)d_in[13];
  float* out = (float*)d_out;

  const int N = in_sizes[0] / NDIM;   // 30000

  float* stok  = (float*)d_ws;                     // 131072
  float* snorm = stok + 131072;                    // 2048
  float* bcomb = snorm + 2048;                     // 256
  int*   seg   = (int*)(bcomb + 256);              // 16
  short* Bt1h  = (short*)(seg + 16);               // 196608
  short* Bt1l  = Bt1h + 196608;
  short* Xh    = Bt1l + 196608;                    // N*256
  short* Xl    = Xh + 7680000;
  short* whb   = Xl + 7680000;                     // NP*256 (padded rows)
  short* wlb   = whb + (size_t)NP * 256;
  short* fxTh  = wlb + (size_t)NP * 256;           // 512*NP
  short* fxTl  = fxTh + (size_t)512 * NP;
  short* PTh   = fxTl + (size_t)512 * NP;          // 524288
  short* PTl   = PTh + 524288;

  hipMemsetAsync(stok, 0, (size_t)(131072 + 2048) * sizeof(float), stream);

  k_xsplit<<<(N * 64 + 255) / 256, 256, 0, stream>>>(x, Xh, Xl, N * 64);

  k_prep<<<769, 256, 0, stream>>>(Wfx, Wx, bx, Wsl, bsl, Bt1h, Bt1l, bcomb);

  k_segs<<<1, 256, 0, stream>>>(batch, seg, N);

  dim3 g1(6, (N + 127) / 128);
  k_fxw<<<g1, 256, 0, stream>>>(Xh, Xl, Bt1h, Bt1l, bfx, bcomb, gtemp,
                                fxTh, fxTl, whb, wlb, N);

  dim3 g2((N + 511) / 512, NH);
  k_scat<<<g2, 256, 0, stream>>>(whb, wlb, fxTh, fxTl, seg, stok, snorm, N);

  k_attn<<<NB * NH, 256, 0, stream>>>(stok, snorm, Wq, Wk, Wv, Wout, PTh, PTl);

  dim3 g5(2, (N + 127) / 128);
  k_outw<<<g5, 256, 0, stream>>>(whb, wlb, PTh, PTl, batch, bout, out, N);
}

// Round 6
// 344.676 us; speedup vs baseline: 1.8486x; 1.1249x over previous
//
#include <hip/hip_runtime.h>

#define NDIM 256
#define INNER 512
#define NH 8
#define ND 64
#define NS 32
#define NB 8
#define NP 30208   // padded node count

typedef __attribute__((ext_vector_type(8))) short short8;   // 8 bf16 = 4 VGPR
typedef __attribute__((ext_vector_type(4))) float f32x4;

static __device__ __forceinline__ short f2bf(float f) {
  unsigned u = __float_as_uint(f);
  unsigned r = (u + 0x7fffu + ((u >> 16) & 1u)) >> 16;
  return (short)r;
}
static __device__ __forceinline__ float bf2f(short s) {
  return __uint_as_float(((unsigned)(unsigned short)s) << 16);
}

// async global->LDS, 16 B per lane; dest = uniform lds base + lane*16
static __device__ __forceinline__ void gl_lds16(const void* g, void* l) {
  __builtin_amdgcn_global_load_lds(
      (const __attribute__((address_space(1))) unsigned int*)g,
      (__attribute__((address_space(3))) unsigned int*)l, 16, 0, 0);
}

// ---------------------------------------------------------------------------
// k_xsplit: x fp32 -> Xh/Xl bf16 hi/lo.
// ---------------------------------------------------------------------------
__global__ __launch_bounds__(256) void k_xsplit(
    const float* __restrict__ x, short* __restrict__ Xh, short* __restrict__ Xl,
    int total4)
{
  int id = blockIdx.x * 256 + threadIdx.x;
  if (id >= total4) return;
  float4 v = *(const float4*)&x[(size_t)id * 4];
  short h0 = f2bf(v.x), h1 = f2bf(v.y), h2 = f2bf(v.z), h3 = f2bf(v.w);
  short4 hv = make_short4(h0, h1, h2, h3);
  short4 lv = make_short4(f2bf(v.x - bf2f(h0)), f2bf(v.y - bf2f(h1)),
                          f2bf(v.z - bf2f(h2)), f2bf(v.w - bf2f(h3)));
  *(short4*)&Xh[(size_t)id * 4] = hv;
  *(short4*)&Xl[(size_t)id * 4] = lv;
}

// ---------------------------------------------------------------------------
// k_prep: Bt1 [768][256] bf16 hi/lo, bcomb[256], seg init.
// ---------------------------------------------------------------------------
__global__ __launch_bounds__(256) void k_prep(
    const float* __restrict__ Wfx, const float* __restrict__ Wx,
    const float* __restrict__ bx, const float* __restrict__ Wsl,
    const float* __restrict__ bsl,
    short* __restrict__ Bt1h, short* __restrict__ Bt1l,
    float* __restrict__ bcomb, int* __restrict__ seg)
{
  int id = blockIdx.x * 256 + threadIdx.x;
  if (id < 131072) {
    int k = id >> 9, n = id & 511;
    float v = Wfx[k * 512 + n];
    short hi = f2bf(v); short lo = f2bf(v - bf2f(hi));
    Bt1h[n * 256 + k] = hi; Bt1l[n * 256 + k] = lo;
  } else if (id < 196608) {
    int e = id - 131072;
    int c = e & 255, k = e >> 8;
    int h = c >> 5, s = c & 31;
    float acc = 0.f;
    #pragma unroll 8
    for (int d = 0; d < 64; d++) acc += Wx[k * 512 + h * 64 + d] * Wsl[d * 32 + s];
    short hi = f2bf(acc); short lo = f2bf(acc - bf2f(hi));
    Bt1h[(512 + c) * 256 + k] = hi; Bt1l[(512 + c) * 256 + k] = lo;
  } else if (id < 196864) {
    int c = id - 196608;
    int h = c >> 5, s = c & 31;
    float acc = bsl[s];
    #pragma unroll 8
    for (int d = 0; d < 64; d++) acc += bx[h * 64 + d] * Wsl[d * 32 + s];
    bcomb[c] = acc;
  } else if (id < 196880) {
    int v = id - 196864;
    seg[v] = (v == 0) ? 0 : 0x7fffffff;
  }
}

// ---------------------------------------------------------------------------
// k_segs: multi-block; seg[b] = first index with batch >= b (batch sorted).
// Requires seg pre-init (k_prep). seg[8..15] tail = N.
// ---------------------------------------------------------------------------
__global__ __launch_bounds__(256) void k_segs(
    const int* __restrict__ batch, int* __restrict__ seg, int N)
{
  int i = blockIdx.x * 256 + threadIdx.x;
  if (i >= N) return;
  int b = batch[i];
  int p = (i == 0) ? -1 : batch[i - 1];
  for (int v = p + 1; v <= b; v++)
    if (v >= 1) atomicMin(&seg[v], i);
  if (i == N - 1)
    for (int v = b + 1; v <= 8; v++) atomicMin(&seg[v], N);
}

// ---------------------------------------------------------------------------
// k_fxw: C[N,768] = x @ Bt1^T, split-3 bf16 MFMA, global_load_lds staging.
// LDS layout per operand tile (128x32 bf16 = 8KB): rowgrp(16 rows)*1KB +
// chunk(8 k)*256B + row16*16B  -> DMA dest = uniform + lane*16; frag reads
// ds_read_b128 2-way-conflict-free.
// 1-D grid, XCD-swizzled: 6 ct-tiles of one row-tile land on one XCD.
// ---------------------------------------------------------------------------
__global__ __launch_bounds__(256) void k_fxw(
    const short* __restrict__ Xh, const short* __restrict__ Xl,
    const short* __restrict__ Bt1h, const short* __restrict__ Bt1l,
    const float* __restrict__ bfx, const float* __restrict__ bcomb,
    const float* __restrict__ gtemp,
    short* __restrict__ fxTh, short* __restrict__ fxTl,
    short* __restrict__ wh_out, short* __restrict__ wl_out,
    int N, int ntiles)
{
  __shared__ __align__(16) short smem[17408];   // 34.8 KB
  short* AhL = &smem[0];        // 4096 shorts each
  short* AlL = &smem[4096];
  short* BhL = &smem[8192];
  short* BlL = &smem[12288];

  const int lid = blockIdx.x;
  const int xcd = lid & 7;
  const int idx = lid >> 3;
  const int ct  = idx % 6;
  const int rowt = xcd + 8 * (idx / 6);
  if (rowt >= ntiles) return;
  const int row0 = rowt * 128;
  const int tid = threadIdx.x;
  const int lane = tid & 63, l15 = lane & 15, quad = lane >> 4;
  const int wvi = tid >> 6, wm = wvi & 1, wn = wvi >> 1;
  const int ctbase = ct * 128;
  const int srow = lane & 15, schunk = lane >> 4;

  f32x4 acc[4][4];
  #pragma unroll
  for (int i = 0; i < 4; i++)
    #pragma unroll
    for (int j = 0; j < 4; j++) acc[i][j] = (f32x4){0.f, 0.f, 0.f, 0.f};

  for (int kt = 0; kt < 8; kt++) {       // K=256, BK=32
    #pragma unroll
    for (int t = 0; t < 2; t++) {
      int g = wvi * 2 + t;               // rowgroup 0..7 (wave-uniform)
      int gr = row0 + g * 16 + srow;
      if (gr > N - 1) gr = N - 1;        // clamp: finite data, never exec-mask
      size_t aoff = (size_t)gr * 256 + kt * 32 + schunk * 8;
      int br = ctbase + g * 16 + srow;
      size_t boff = (size_t)br * 256 + kt * 32 + schunk * 8;
      gl_lds16(Xh + aoff, AhL + g * 512);
      gl_lds16(Xl + aoff, AlL + g * 512);
      gl_lds16(Bt1h + boff, BhL + g * 512);
      gl_lds16(Bt1l + boff, BlL + g * 512);
    }
    __syncthreads();

    short8 ah[4], al[4];
    #pragma unroll
    for (int mt = 0; mt < 4; mt++) {
      int rg = wm * 4 + mt;
      ah[mt] = *(const short8*)&AhL[rg * 512 + quad * 128 + l15 * 8];
      al[mt] = *(const short8*)&AlL[rg * 512 + quad * 128 + l15 * 8];
    }
    #pragma unroll
    for (int nt = 0; nt < 4; nt++) {
      int rg = wn * 4 + nt;
      short8 bh = *(const short8*)&BhL[rg * 512 + quad * 128 + l15 * 8];
      short8 bl = *(const short8*)&BlL[rg * 512 + quad * 128 + l15 * 8];
      #pragma unroll
      for (int mt = 0; mt < 4; mt++) {
        acc[mt][nt] = __builtin_amdgcn_mfma_f32_16x16x32_bf16(ah[mt], bh, acc[mt][nt], 0, 0, 0);
        acc[mt][nt] = __builtin_amdgcn_mfma_f32_16x16x32_bf16(ah[mt], bl, acc[mt][nt], 0, 0, 0);
        acc[mt][nt] = __builtin_amdgcn_mfma_f32_16x16x32_bf16(al[mt], bh, acc[mt][nt], 0, 0, 0);
      }
    }
    __syncthreads();
  }

  if (ct < 4) {
    // two-pass LDS transpose -> fxT[c][n] bf16 hi (pass 0) / lo (pass 1)
    short (*T)[136] = (short(*)[136])&smem[0];   // 128 x 136 = 17408 shorts
    #pragma unroll
    for (int pass = 0; pass < 2; pass++) {
      __syncthreads();
      #pragma unroll
      for (int nt = 0; nt < 4; nt++) {
        int cl = wn * 64 + nt * 16 + l15;
        float bias = bfx[ctbase + cl];
        #pragma unroll
        for (int mt = 0; mt < 4; mt++)
          #pragma unroll
          for (int r = 0; r < 4; r++) {
            int rl = wm * 64 + mt * 16 + quad * 4 + r;
            float v = acc[mt][nt][r] + bias;
            short hi2 = f2bf(v);
            T[cl][rl] = pass ? f2bf(v - bf2f(hi2)) : hi2;
          }
      }
      __syncthreads();
      short* dst = pass ? fxTl : fxTh;
      #pragma unroll
      for (int t = 0; t < 8; t++) {
        int idx2 = tid + t * 256;                 // 2048 int4 chunks
        int row = idx2 >> 4, kc = (idx2 & 15) * 8;
        *(int4*)&dst[(size_t)(ctbase + row) * NP + row0 + kc] = *(const int4*)&T[row][kc];
      }
    }
  } else {
    int ct2 = ct - 4;
    #pragma unroll
    for (int g = 0; g < 2; g++) {
      int lcbase = ct2 * 128 + wn * 64 + g * 32;
      int h = lcbase >> 5;
      float inv_t = 1.0f / gtemp[h];
      int lc0 = lcbase + l15, lc1 = lcbase + 16 + l15;
      float b0 = bcomb[lc0], b1 = bcomb[lc1];
      #pragma unroll
      for (int mt = 0; mt < 4; mt++) {
        #pragma unroll
        for (int r = 0; r < 4; r++) {
          float s0 = (acc[mt][2 * g + 0][r] + b0) * inv_t;
          float s1 = (acc[mt][2 * g + 1][r] + b1) * inv_t;
          float m = fmaxf(s0, s1);
          #pragma unroll
          for (int off = 1; off < 16; off <<= 1) m = fmaxf(m, __shfl_xor(m, off, 16));
          float e0 = __expf(s0 - m), e1 = __expf(s1 - m);
          float sum = e0 + e1;
          #pragma unroll
          for (int off = 1; off < 16; off <<= 1) sum += __shfl_xor(sum, off, 16);
          float inv = 1.0f / sum;
          int row = row0 + wm * 64 + mt * 16 + quad * 4 + r;
          if (row < N) {
            float w0v = e0 * inv, w1v = e1 * inv;
            size_t base = (size_t)row * (NH * NS);
            short h0 = f2bf(w0v), h1 = f2bf(w1v);
            wh_out[base + lc0] = h0; wl_out[base + lc0] = f2bf(w0v - bf2f(h0));
            wh_out[base + lc1] = h1; wl_out[base + lc1] = f2bf(w1v - bf2f(h1));
          }
        }
      }
    }
  }
}

// ---------------------------------------------------------------------------
// k_scat: slice_token[b,h,s,d] = sum_n w[n,hs]*fx[n,hd], split-3 MFMA over
// K=nodes. w staged via LDS transpose with segment masking folded into the
// store -> A-fragments are ds_read_b128. Per-segment atomic flush.
// ---------------------------------------------------------------------------
__global__ __launch_bounds__(256) void k_scat(
    const short* __restrict__ wh, const short* __restrict__ wl,
    const short* __restrict__ fxTh, const short* __restrict__ fxTl,
    const int* __restrict__ seg,
    float* __restrict__ stok, float* __restrict__ snorm, int N)
{
  __shared__ short wth[32][136];     // [s][n], masked
  __shared__ short wtl[32][136];
  __shared__ short fh[64][136];      // [d][n]
  __shared__ short fl[64][136];
  __shared__ float ln[32];

  const int h = blockIdx.y;
  const int n0 = blockIdx.x * 512;
  const int tid = threadIdx.x;
  const int lane = tid & 63, l15 = lane & 15, quad = lane >> 4;
  const int wv = tid >> 6;
  const int nend = min(n0 + 512, N);

  f32x4 acc0 = (f32x4){0.f, 0.f, 0.f, 0.f};   // s rows 0..15
  f32x4 acc1 = (f32x4){0.f, 0.f, 0.f, 0.f};   // s rows 16..31

  for (int b = 0; b < NB; b++) {
    int lo = max(seg[b], n0), hi = min(seg[b + 1], nend);
    if (lo >= hi) continue;
    if (tid < 32) ln[tid] = 0.f;
    int c0lo = (lo - n0) & ~127;
    int c0hi = hi - n0;
    for (int c0 = c0lo; c0 < c0hi; c0 += 128) {
      __syncthreads();
      #pragma unroll
      for (int t = 0; t < 2; t++) {           // w: coalesced read, transposed+masked store
        int idx2 = tid + t * 256;             // 0..511
        int row = idx2 >> 2;                  // n-local 0..127
        int sc  = (idx2 & 3) * 8;
        int ng = n0 + c0 + row;
        short8 vh = (short8){0,0,0,0,0,0,0,0};
        short8 vl = (short8){0,0,0,0,0,0,0,0};
        if (ng >= lo && ng < hi) {
          size_t src = (size_t)ng * 256 + h * 32 + sc;
          vh = *(const short8*)&wh[src];
          vl = *(const short8*)&wl[src];
        }
        #pragma unroll
        for (int j = 0; j < 8; j++) {
          wth[sc + j][row] = vh[j];
          wtl[sc + j][row] = vl[j];
        }
      }
      #pragma unroll
      for (int t = 0; t < 4; t++) {           // fxT rows (64 d x 128 n)
        int idx2 = tid + t * 256;
        int row = idx2 >> 4, kc = (idx2 & 15) * 8;
        size_t src = (size_t)(h * 64 + row) * NP + n0 + c0 + kc;
        *(int4*)&fh[row][kc] = *(const int4*)&fxTh[src];
        *(int4*)&fl[row][kc] = *(const int4*)&fxTl[src];
      }
      __syncthreads();

      { // snorm from masked w tiles
        int s = tid >> 3, g = tid & 7;
        float sum = 0.f;
        #pragma unroll
        for (int i2 = 0; i2 < 16; i2++) {
          int nl = g * 16 + i2;
          sum += bf2f(wth[s][nl]) + bf2f(wtl[s][nl]);
        }
        atomicAdd(&ln[s], sum);
      }

      for (int k0 = 0; k0 < 128; k0 += 32) {
        int gbase = n0 + c0 + k0;
        if (gbase + 32 <= lo || gbase >= hi) continue;
        short8 a0h = *(const short8*)&wth[l15][k0 + quad * 8];
        short8 a0l = *(const short8*)&wtl[l15][k0 + quad * 8];
        short8 a1h = *(const short8*)&wth[16 + l15][k0 + quad * 8];
        short8 a1l = *(const short8*)&wtl[16 + l15][k0 + quad * 8];
        short8 bh = *(const short8*)&fh[wv * 16 + l15][k0 + quad * 8];
        short8 bl = *(const short8*)&fl[wv * 16 + l15][k0 + quad * 8];
        acc0 = __builtin_amdgcn_mfma_f32_16x16x32_bf16(a0h, bh, acc0, 0, 0, 0);
        acc0 = __builtin_amdgcn_mfma_f32_16x16x32_bf16(a0h, bl, acc0, 0, 0, 0);
        acc0 = __builtin_amdgcn_mfma_f32_16x16x32_bf16(a0l, bh, acc0, 0, 0, 0);
        acc1 = __builtin_amdgcn_mfma_f32_16x16x32_bf16(a1h, bh, acc1, 0, 0, 0);
        acc1 = __builtin_amdgcn_mfma_f32_16x16x32_bf16(a1h, bl, acc1, 0, 0, 0);
        acc1 = __builtin_amdgcn_mfma_f32_16x16x32_bf16(a1l, bh, acc1, 0, 0, 0);
      }
    }
    __syncthreads();
    size_t base = ((size_t)b * NH + h) * NS;
    #pragma unroll
    for (int r = 0; r < 4; r++) {
      atomicAdd(&stok[(base + quad * 4 + r) * ND + wv * 16 + l15], acc0[r]);
      atomicAdd(&stok[(base + 16 + quad * 4 + r) * ND + wv * 16 + l15], acc1[r]);
    }
    if (tid < 32) atomicAdd(&snorm[base + tid], ln[tid]);
    acc0 = (f32x4){0.f, 0.f, 0.f, 0.f};
    acc1 = (f32x4){0.f, 0.f, 0.f, 0.f};
    __syncthreads();
  }
}

// ---------------------------------------------------------------------------
// k_attn: per (b,h): normalize tokens, q/k/v, 32x32 attention, out_tok (LDS),
// then P[s][c] = sum_d out_tok[s][d]*Wout[h*64+d][c]; store P^T bf16 hi/lo.
// ---------------------------------------------------------------------------
__global__ __launch_bounds__(256) void k_attn(
    const float* __restrict__ stok, const float* __restrict__ snorm,
    const float* __restrict__ Wq, const float* __restrict__ Wk,
    const float* __restrict__ Wv, const float* __restrict__ Wout,
    short* __restrict__ PTh, short* __restrict__ PTl)
{
  __shared__ float st[32][65];
  __shared__ float qs[32][65];
  __shared__ float ks[32][65];
  __shared__ float vs[32][65];
  __shared__ float at[32][33];
  __shared__ float ot[32][65];
  const int bh = blockIdx.x;
  const int b = bh >> 3, h = bh & 7;
  const int tid = threadIdx.x;

  for (int i = tid; i < 2048; i += 256) {
    int ss = i >> 6;
    float nrm = snorm[(size_t)bh * NS + ss] + 1e-5f;
    st[ss][i & 63] = stok[(size_t)bh * 2048 + i] / nrm;
  }
  __syncthreads();

  const int e = tid & 63, sgp = tid >> 6;
  for (int ii = 0; ii < 8; ii++) {
    int ss = sgp * 8 + ii;
    float aq = 0.f, ak = 0.f, av = 0.f;
    #pragma unroll 8
    for (int dd = 0; dd < 64; dd++) {
      float sv = st[ss][dd];
      aq += sv * Wq[dd * 64 + e];
      ak += sv * Wk[dd * 64 + e];
      av += sv * Wv[dd * 64 + e];
    }
    qs[ss][e] = aq; ks[ss][e] = ak; vs[ss][e] = av;
  }
  __syncthreads();

  const float scale = 0.125f;
  for (int i = tid; i < 1024; i += 256) {
    int si = i >> 5, tj = i & 31;
    float a = 0.f;
    #pragma unroll 8
    for (int ee = 0; ee < 64; ee++) a += qs[si][ee] * ks[tj][ee];
    at[si][tj] = a * scale;
  }
  __syncthreads();

  if (tid < 32) {
    float m = -1e30f;
    for (int j = 0; j < 32; j++) m = fmaxf(m, at[tid][j]);
    float sum = 0.f;
    for (int j = 0; j < 32; j++) { float ev = __expf(at[tid][j] - m); at[tid][j] = ev; sum += ev; }
    float inv = 1.f / sum;
    for (int j = 0; j < 32; j++) at[tid][j] *= inv;
  }
  __syncthreads();

  for (int ii = 0; ii < 8; ii++) {
    int ss = sgp * 8 + ii;
    float a = 0.f;
    #pragma unroll 8
    for (int tj = 0; tj < 32; tj++) a += at[ss][tj] * vs[tj][e];
    ot[ss][e] = a;
  }
  __syncthreads();

  const int s_p = tid >> 3;
  const int c0 = (tid & 7) * 32;
  float pacc[32];
  #pragma unroll
  for (int q = 0; q < 32; q++) pacc[q] = 0.f;
  for (int dd = 0; dd < 64; dd++) {
    float o = ot[s_p][dd];
    const float4* wr = (const float4*)&Wout[(size_t)(h * 64 + dd) * NDIM + c0];
    #pragma unroll
    for (int q = 0; q < 8; q++) {
      float4 v = wr[q];
      pacc[4 * q + 0] += o * v.x;
      pacc[4 * q + 1] += o * v.y;
      pacc[4 * q + 2] += o * v.z;
      pacc[4 * q + 3] += o * v.w;
    }
  }
  #pragma unroll
  for (int q = 0; q < 32; q++) {
    int c = c0 + q;
    float val = pacc[q];
    short hi = f2bf(val);
    size_t dst = ((size_t)b * NDIM + c) * 256 + h * 32 + s_p;
    PTh[dst] = hi;
    PTl[dst] = f2bf(val - bf2f(hi));
  }
}

// ---------------------------------------------------------------------------
// k_outw: out[n,c] = sum_{hs} w[n,hs] * PT[batch[n]][c][hs] + bout[c].
// ---------------------------------------------------------------------------
__global__ __launch_bounds__(256) void k_outw(
    const short* __restrict__ wh, const short* __restrict__ wl,
    const short* __restrict__ PTh, const short* __restrict__ PTl,
    const int* __restrict__ batch, const float* __restrict__ bout,
    float* __restrict__ out, int N)
{
  __shared__ short Ah[128][40];
  __shared__ short Al[128][40];
  __shared__ short Bh[128][40];
  __shared__ short Bl[128][40];
  __shared__ int b_sh[128];

  const int ct = blockIdx.x;
  const int row0 = blockIdx.y * 128;
  const int tid = threadIdx.x;
  const int lane = tid & 63, l15 = lane & 15, quad = lane >> 4;
  const int wv = tid >> 6, wm = wv & 1, wn = wv >> 1;
  const int ctbase = ct * 128;
  const int cnt = min(128, N - row0);

  if (tid < 128) b_sh[tid] = (tid < cnt) ? batch[row0 + tid] : -1;
  __syncthreads();

  f32x4 acc[4][4];
  #pragma unroll
  for (int i = 0; i < 4; i++)
    #pragma unroll
    for (int j = 0; j < 4; j++) acc[i][j] = (f32x4){0.f, 0.f, 0.f, 0.f};

  int i0 = 0;
  while (i0 < cnt) {
    int b = b_sh[i0];
    int j = i0;
    while (j < cnt && b_sh[j] == b) j++;

    for (int kt = 0; kt < 8; kt++) {
      #pragma unroll
      for (int t = 0; t < 2; t++) {
        int i = tid + t * 256;
        int row = i >> 2, kc = (i & 3) * 8;
        int4 vh = make_int4(0, 0, 0, 0), vl = make_int4(0, 0, 0, 0);
        if (row >= i0 && row < j) {
          size_t src = (size_t)(row0 + row) * 256 + kt * 32 + kc;
          vh = *(const int4*)&wh[src];
          vl = *(const int4*)&wl[src];
        }
        *(int4*)&Ah[row][kc] = vh;
        *(int4*)&Al[row][kc] = vl;
      }
      #pragma unroll
      for (int t = 0; t < 2; t++) {
        int i = tid + t * 256;
        int row = i >> 2, kc = (i & 3) * 8;
        size_t src = ((size_t)b * NDIM + ctbase + row) * 256 + kt * 32 + kc;
        *(int4*)&Bh[row][kc] = *(const int4*)&PTh[src];
        *(int4*)&Bl[row][kc] = *(const int4*)&PTl[src];
      }
      __syncthreads();

      short8 ah[4], al[4];
      #pragma unroll
      for (int mt = 0; mt < 4; mt++) {
        int m = wm * 64 + mt * 16 + l15;
        ah[mt] = *(const short8*)&Ah[m][quad * 8];
        al[mt] = *(const short8*)&Al[m][quad * 8];
      }
      #pragma unroll
      for (int nt = 0; nt < 4; nt++) {
        int n = wn * 64 + nt * 16 + l15;
        short8 bh = *(const short8*)&Bh[n][quad * 8];
        short8 bl = *(const short8*)&Bl[n][quad * 8];
        #pragma unroll
        for (int mt = 0; mt < 4; mt++) {
          acc[mt][nt] = __builtin_amdgcn_mfma_f32_16x16x32_bf16(ah[mt], bh, acc[mt][nt], 0, 0, 0);
          acc[mt][nt] = __builtin_amdgcn_mfma_f32_16x16x32_bf16(ah[mt], bl, acc[mt][nt], 0, 0, 0);
          acc[mt][nt] = __builtin_amdgcn_mfma_f32_16x16x32_bf16(al[mt], bh, acc[mt][nt], 0, 0, 0);
        }
      }
      __syncthreads();
    }
    i0 = j;
  }

  #pragma unroll
  for (int nt = 0; nt < 4; nt++) {
    int c = ctbase + wn * 64 + nt * 16 + l15;
    float bias = bout[c];
    #pragma unroll
    for (int mt = 0; mt < 4; mt++)
      #pragma unroll
      for (int r = 0; r < 4; r++) {
        int row = row0 + wm * 64 + mt * 16 + quad * 4 + r;
        if (row < N) out[(size_t)row * NDIM + c] = acc[mt][nt][r] + bias;
      }
  }
}

// ---------------------------------------------------------------------------
extern "C" void kernel_launch(void* const* d_in, const int* in_sizes, int n_in,
                              void* d_out, int out_size, void* d_ws, size_t ws_size,
                              hipStream_t stream) {
  const float* x      = (const float*)d_in[0];
  const int*   batch  = (const int*)d_in[1];
  const float* Wfx    = (const float*)d_in[2];
  const float* bfx    = (const float*)d_in[3];
  const float* Wx     = (const float*)d_in[4];
  const float* bx     = (const float*)d_in[5];
  const float* Wsl    = (const float*)d_in[6];
  const float* bsl    = (const float*)d_in[7];
  const float* gtemp  = (const float*)d_in[8];
  const float* Wq     = (const float*)d_in[9];
  const float* Wk     = (const float*)d_in[10];
  const float* Wv     = (const float*)d_in[11];
  const float* Wout   = (const float*)d_in[12];
  const float* bout   = (const float*)d_in[13];
  float* out = (float*)d_out;

  const int N = in_sizes[0] / NDIM;   // 30000

  float* stok  = (float*)d_ws;                     // 131072
  float* snorm = stok + 131072;                    // 2048
  float* bcomb = snorm + 2048;                     // 256
  int*   seg   = (int*)(bcomb + 256);              // 16
  short* Bt1h  = (short*)(seg + 16);               // 196608
  short* Bt1l  = Bt1h + 196608;
  short* Xh    = Bt1l + 196608;                    // N*256
  short* Xl    = Xh + 7680000;
  short* whb   = Xl + 7680000;                     // NP*256
  short* wlb   = whb + (size_t)NP * 256;
  short* fxTh  = wlb + (size_t)NP * 256;           // 512*NP
  short* fxTl  = fxTh + (size_t)512 * NP;
  short* PTh   = fxTl + (size_t)512 * NP;          // 524288
  short* PTl   = PTh + 524288;

  hipMemsetAsync(stok, 0, (size_t)(131072 + 2048) * sizeof(float), stream);

  k_xsplit<<<(N * 64 + 255) / 256, 256, 0, stream>>>(x, Xh, Xl, N * 64);

  k_prep<<<770, 256, 0, stream>>>(Wfx, Wx, bx, Wsl, bsl, Bt1h, Bt1l, bcomb, seg);

  k_segs<<<(N + 255) / 256, 256, 0, stream>>>(batch, seg, N);

  const int ntiles = (N + 127) / 128;               // 235
  const int qmax = (ntiles + 7) / 8;                // 30
  k_fxw<<<8 * qmax * 6, 256, 0, stream>>>(Xh, Xl, Bt1h, Bt1l, bfx, bcomb, gtemp,
                                          fxTh, fxTl, whb, wlb, N, ntiles);

  dim3 g2((N + 511) / 512, NH);
  k_scat<<<g2, 256, 0, stream>>>(whb, wlb, fxTh, fxTl, seg, stok, snorm, N);

  k_attn<<<NB * NH, 256, 0, stream>>>(stok, snorm, Wq, Wk, Wv, Wout, PTh, PTl);

  dim3 g5(2, (N + 127) / 128);
  k_outw<<<g5, 256, 0, stream>>>(whb, wlb, PTh, PTl, batch, bout, out, N);
}